// Round 6
// baseline (454.903 us; speedup 1.0000x reference)
//
#include <hip/hip_runtime.h>
#include <hip/hip_bf16.h>

#define NSP   20000
#define NSPAT 10000
#define ESS   160000
#define EBIP  320000
#define ESP   320000

static inline int cdiv_host(long a, long b) { return (int)((a + b - 1) / b); }

__device__ __forceinline__ float wave_red_sum(float p) {
#pragma unroll
  for (int m = 32; m >= 1; m >>= 1) p += __shfl_xor(p, m, 64);
  return p;
}
__device__ __forceinline__ float bf2f(unsigned short u) {
  return __uint_as_float(((unsigned int)u) << 16);
}
__device__ __forceinline__ unsigned short f2bf(float f) {
  unsigned int u = __float_as_uint(f);
  unsigned int r = (u + 0x7FFF + ((u >> 16) & 1)) >> 16;  // RN-even
  return (unsigned short)r;
}
__device__ __forceinline__ float lrelu(float x) {
  return (x > 0.f) ? x : 0.2f * x;
}

struct DoteArgs { const float* We[5]; const float* ae[5]; float* dotes; };
struct PrepArgs {
  const float* mean; const float* stdv; const void* mask;
  const float* sx; const float* sg; float* spc96; float* h0;
};

// ---------------------------------------------------------------------------
// L1: CSR count (8-way partitioned atomics, [p][n] layout) + dote dot-products
// + spc96/h0 prep, one launch.  NO per-node float atomics (leaf-mean is
// computed inline in the GAT kernels from csr_ea).
// ---------------------------------------------------------------------------
__global__ void count3x_kernel(
    const int* c1, int* cp1, int* rnk1, int n1, int E1,
    const int* c2, int* cp2, int* rnk2, int n2, int E2,
    const int* c3, int* cp3, int* rnk3, int n3, int E3,
    DoteArgs da, PrepArgs pa) {
  const int NB_E = (ESS + EBIP + ESP + 255) / 256;   // 3125
  int b = blockIdx.x, t = threadIdx.x;
  if (b < NB_E) {
    int i = b * 256 + t;
    if (i >= E1 + E2 + E3) return;
    int p = (i >> 8) & 7;
    if (i < E1) {
      int d = c1[i];
      rnk1[i] = atomicAdd(&cp1[p * n1 + d], 1);
    } else if (i < E1 + E2) {
      int j = i - E1;
      int d = c2[j];
      rnk2[j] = atomicAdd(&cp2[p * n2 + d], 1);
    } else {
      int j = i - E1 - E2;
      int d = c3[j];
      rnk3[j] = atomicAdd(&cp3[p * n3 + d], 1);
    }
  } else if (b < NB_E + 5) {
    int lb = b - NB_E;
    int n = (lb == 2) ? 64 : 256;
    if (t < n) {
      float p = wave_red_sum(da.We[lb][t] * da.ae[lb][t]);
      if ((t & 63) == 0) da.dotes[lb * 4 + (t >> 6)] = p;
    }
  } else {
    // prep blocks: per-block mask-format detect (reads 1KB broadcast)
    __shared__ int sflag;
    if (t < 64) {
      const unsigned int* mw = (const unsigned int*)pa.mask;
      unsigned int w0 = mw[t], w1 = mw[t + 64], w2 = mw[t + 128], w3 = mw[t + 192];
      bool ai = (w0 <= 1u) && (w1 <= 1u) && (w2 <= 1u) && (w3 <= 1u);
      auto okf = [](unsigned int w) { return w == 0u || w == 0x3f800000u; };
      bool af = okf(w0) && okf(w1) && okf(w2) && okf(w3);
      unsigned long long bi = __ballot(ai), bf = __ballot(af);
      if (t == 0) sflag = (bi == ~0ull) ? 0 : ((bf == ~0ull) ? 2 : 1);
    }
    __syncthreads();
    int mode = sflag;
    const long totA = (long)NSP * 96;
    const long totB = (long)NSPAT * 16;
    long i = (long)(b - NB_E - 5) * 256 + t;
    if (i >= totA + totB) return;
    if (i < totA) {
      int n = (int)(i / 96), c = (int)(i % 96);
      float v;
      if (c < 32) v = pa.mean[(long)n * 32 + c];
      else if (c < 64) v = pa.stdv[(long)n * 32 + (c - 32)];
      else {
        long j = (long)n * 32 + (c - 64);
        int mv;
        if (mode == 0) mv = ((const int*)pa.mask)[j];
        else if (mode == 2) mv = (((const float*)pa.mask)[j] != 0.0f);
        else mv = (int)((const unsigned char*)pa.mask)[j];
        v = mv ? 0.f : 1.f;   // vis = ~mask
      }
      pa.spc96[i] = v;
    } else {
      long k = i - totA;
      int n = (int)(k / 16), c = (int)(k % 16);
      pa.h0[k] = (c < 12) ? pa.sx[(long)n * 12 + c] : pa.sg[(long)n * 4 + (c - 12)];
    }
  }
}

// L2: per-node partition merge (coalesced per partition)
__global__ void merge3_kernel(int* cp1, int* c1, int n1,
                              int* cp2, int* c2, int n2,
                              int* cp3, int* c3, int n3) {
  int i = blockIdx.x * blockDim.x + threadIdx.x;
  int total = n1 + n2 + n3;
  if (i >= total) return;
  int *cp, *c; int n, d;
  if (i < n1) { cp = cp1; c = c1; n = n1; d = i; }
  else if (i < n1 + n2) { cp = cp2; c = c2; n = n2; d = i - n1; }
  else { cp = cp3; c = c3; n = n3; d = i - n1 - n2; }
  int s = 0;
#pragma unroll
  for (int p = 0; p < 8; ++p) { int t = cp[p * n + d]; cp[p * n + d] = s; s += t; }
  c[d] = s;
}

// L3: three block-wide exclusive scans
__global__ __launch_bounds__(1024) void scan3_kernel(
    const int* cntA, int nA, int* ptrA,
    const int* cntB, int nB, int* ptrB,
    const int* cntC, int nC, int* ptrC) {
  const int* cnt; int n; int* ptr;
  if (blockIdx.x == 0) { cnt = cntA; n = nA; ptr = ptrA; }
  else if (blockIdx.x == 1) { cnt = cntB; n = nB; ptr = ptrB; }
  else { cnt = cntC; n = nC; ptr = ptrC; }
  __shared__ int part[1024];
  int t = threadIdx.x;
  int ch = (n + 1023) / 1024;
  int beg = t * ch, end = min(beg + ch, n);
  int s = 0;
  for (int i = beg; i < end; ++i) s += cnt[i];
  part[t] = s;
  __syncthreads();
  for (int off = 1; off < 1024; off <<= 1) {
    int v = (t >= off) ? part[t - off] : 0;
    __syncthreads();
    part[t] += v;
    __syncthreads();
  }
  int run = (t == 0) ? 0 : part[t - 1];
  for (int i = beg; i < end; ++i) { ptr[i] = run; run += cnt[i]; }
  if (t == 1023) ptr[n] = part[1023];
}

struct XSrc { const float* p[5]; int w[5]; int n; };
struct PJob {
  XSrc xs; int M, K;
  const float* W; const float* bias; int mode;
  const float* a_s; const float* a_d;
  float* al_s; float* al_d;
  float* Y; float* Y2;
};

// ---------------------------------------------------------------------------
// NOUT=64 projection body, tiled: BR=32 rows/block, KC=32.  4 cols x 2 rows.
// mode: 0 plain (skip store if Y null), 1 bias+relu, 2 final split.
// ---------------------------------------------------------------------------
__device__ __forceinline__ void proj64_body(const PJob& J, int bid,
                                            float* wl, float* xl) {
  constexpr int KC = 32;
  constexpr int BR = 32;
  constexpr int KCP = 36;
  int t = threadIdx.x;
  long row0 = (long)bid * BR;
  if (row0 >= J.M) return;
  int cg = t & 15, rg = t >> 4;
  int c0 = cg * 4;

  float acc[2][4];
#pragma unroll
  for (int r = 0; r < 2; ++r)
#pragma unroll
    for (int j = 0; j < 4; ++j) acc[r][j] = 0.f;

  for (int k0 = 0; k0 < J.K; k0 += KC) {
    int seg = 0; int base = 0;
    while (k0 >= base + J.xs.w[seg]) { base += J.xs.w[seg]; ++seg; }
    const float* Xp = J.xs.p[seg];
    int stride = J.xs.w[seg];
    int kloc = k0 - base;

    __syncthreads();
    {
      const float4* ws = (const float4*)(J.W + (long)k0 * 64);
      float4* wd = (float4*)wl;
      wd[t] = ws[t];
      wd[t + 256] = ws[t + 256];
    }
    {
      int r = t >> 3, kq = (t & 7) * 4;
      long rr = row0 + r; if (rr >= J.M) rr = J.M - 1;
      float4 v = *(const float4*)(Xp + rr * stride + kloc + kq);
      *(float4*)(xl + r * KCP + kq) = v;
    }
    __syncthreads();

    for (int kg = 0; kg < KC; kg += 4) {
      float4 w0 = *(const float4*)(wl + (kg + 0) * 64 + c0);
      float4 w1 = *(const float4*)(wl + (kg + 1) * 64 + c0);
      float4 w2 = *(const float4*)(wl + (kg + 2) * 64 + c0);
      float4 w3 = *(const float4*)(wl + (kg + 3) * 64 + c0);
#pragma unroll
      for (int r = 0; r < 2; ++r) {
        float4 xv = *(const float4*)(xl + (rg * 2 + r) * KCP + kg);
        acc[r][0] = fmaf(xv.x, w0.x, acc[r][0]);
        acc[r][1] = fmaf(xv.x, w0.y, acc[r][1]);
        acc[r][2] = fmaf(xv.x, w0.z, acc[r][2]);
        acc[r][3] = fmaf(xv.x, w0.w, acc[r][3]);
        acc[r][0] = fmaf(xv.y, w1.x, acc[r][0]);
        acc[r][1] = fmaf(xv.y, w1.y, acc[r][1]);
        acc[r][2] = fmaf(xv.y, w1.z, acc[r][2]);
        acc[r][3] = fmaf(xv.y, w1.w, acc[r][3]);
        acc[r][0] = fmaf(xv.z, w2.x, acc[r][0]);
        acc[r][1] = fmaf(xv.z, w2.y, acc[r][1]);
        acc[r][2] = fmaf(xv.z, w2.z, acc[r][2]);
        acc[r][3] = fmaf(xv.z, w2.w, acc[r][3]);
        acc[r][0] = fmaf(xv.w, w3.x, acc[r][0]);
        acc[r][1] = fmaf(xv.w, w3.y, acc[r][1]);
        acc[r][2] = fmaf(xv.w, w3.z, acc[r][2]);
        acc[r][3] = fmaf(xv.w, w3.w, acc[r][3]);
      }
    }
  }

  float4 bv = make_float4(0.f, 0.f, 0.f, 0.f);
  float4 asv = make_float4(0.f, 0.f, 0.f, 0.f);
  float4 adv = make_float4(0.f, 0.f, 0.f, 0.f);
  if (J.bias) bv = *(const float4*)(J.bias + c0);
  if (J.a_s) asv = *(const float4*)(J.a_s + c0);
  if (J.a_d) adv = *(const float4*)(J.a_d + c0);

#pragma unroll
  for (int r = 0; r < 2; ++r) {
    long m = row0 + rg * 2 + r;
    bool ok = m < J.M;
    float v0 = acc[r][0] + bv.x, v1 = acc[r][1] + bv.y;
    float v2 = acc[r][2] + bv.z, v3 = acc[r][3] + bv.w;
    if (J.mode == 1) {
      if (ok)
        *(float4*)(J.Y + m * 64 + c0) = make_float4(
            fmaxf(v0, 0.f), fmaxf(v1, 0.f), fmaxf(v2, 0.f), fmaxf(v3, 0.f));
    } else if (J.mode == 2) {
      if (ok) {
        if (c0 < 32) {
          *(float4*)(J.Y + m * 32 + c0) = make_float4(v0, v1, v2, v3);
        } else {
          float4 o;
          o.x = fmaxf(v0, 0.f) + log1pf(__expf(-fabsf(v0))) + 1e-6f;
          o.y = fmaxf(v1, 0.f) + log1pf(__expf(-fabsf(v1))) + 1e-6f;
          o.z = fmaxf(v2, 0.f) + log1pf(__expf(-fabsf(v2))) + 1e-6f;
          o.w = fmaxf(v3, 0.f) + log1pf(__expf(-fabsf(v3))) + 1e-6f;
          *(float4*)(J.Y2 + m * 32 + (c0 - 32)) = o;
        }
      }
    } else if (ok && J.Y) {
      *(float4*)(J.Y + m * 64 + c0) = make_float4(v0, v1, v2, v3);
    }
    if (J.a_s) {
      float s = acc[r][0] * asv.x + acc[r][1] * asv.y + acc[r][2] * asv.z + acc[r][3] * asv.w;
      s += __shfl_xor(s, 1); s += __shfl_xor(s, 2);
      s += __shfl_xor(s, 4); s += __shfl_xor(s, 8);
      if (ok && cg == 0) J.al_s[m] = s;
    }
    if (J.a_d) {
      float s = acc[r][0] * adv.x + acc[r][1] * adv.y + acc[r][2] * adv.z + acc[r][3] * adv.w;
      s += __shfl_xor(s, 1); s += __shfl_xor(s, 2);
      s += __shfl_xor(s, 4); s += __shfl_xor(s, 8);
      if (ok && cg == 0) J.al_d[m] = s;
    }
  }
}

// ---------------------------------------------------------------------------
// NOUT=256 projection body (tiled, BR=32, KC=16 to halve LDS -> 7 blocks/CU).
// X and W staged in LDS.  bf16 out.
// ---------------------------------------------------------------------------
__device__ __forceinline__ void proj256_body(
    const XSrc& xsrc, int M, int K,
    const float* __restrict__ W,
    const float* __restrict__ a_s, const float* __restrict__ a_d,
    float* __restrict__ al_s, float* __restrict__ al_d,
    unsigned short* __restrict__ Y, int bid, float* wl, float* xl) {
  constexpr int KC = 16;
  constexpr int RPT = 8;
  constexpr int BR = 32;
  constexpr int KCP = 20;
  constexpr int H = 4;
  int t = threadIdx.x;
  int cg = t & 63, rg = t >> 6;
  int c0 = cg * 4;
  long row0 = (long)bid * BR;
  if (row0 >= M) return;

  float acc[RPT][4];
#pragma unroll
  for (int r = 0; r < RPT; ++r)
#pragma unroll
    for (int j = 0; j < 4; ++j) acc[r][j] = 0.f;

  for (int k0 = 0; k0 < K; k0 += KC) {
    int kc = min(KC, K - k0);
    int seg = 0; int base = 0;
    while (k0 >= base + xsrc.w[seg]) { base += xsrc.w[seg]; ++seg; }
    const float* Xp = xsrc.p[seg];
    int stride = xsrc.w[seg];
    int kloc = k0 - base;

    __syncthreads();
    {
      const float4* wsrc = (const float4*)(W + (long)k0 * 256);
      float4* wdst = (float4*)wl;
      for (int i = t; i < (kc * 256) >> 2; i += 256) wdst[i] = wsrc[i];
    }
    for (int i = t; i < BR * 4; i += 256) {
      int r = i >> 2, kq = (i & 3) * 4;
      if (kq < kc) {
        long rr = row0 + r; if (rr >= M) rr = M - 1;
        float4 v = *(const float4*)(Xp + rr * stride + kloc + kq);
        *(float4*)(xl + r * KCP + kq) = v;
      }
    }
    __syncthreads();

    for (int kg = 0; kg < kc; kg += 4) {
      float4 w0 = *(const float4*)(wl + (kg + 0) * 256 + c0);
      float4 w1 = *(const float4*)(wl + (kg + 1) * 256 + c0);
      float4 w2 = *(const float4*)(wl + (kg + 2) * 256 + c0);
      float4 w3 = *(const float4*)(wl + (kg + 3) * 256 + c0);
      float4 xv[RPT];
#pragma unroll
      for (int r = 0; r < RPT; ++r)
        xv[r] = *(const float4*)(xl + (rg * RPT + r) * KCP + kg);
#pragma unroll
      for (int r = 0; r < RPT; ++r) {
        acc[r][0] = fmaf(xv[r].x, w0.x, acc[r][0]);
        acc[r][1] = fmaf(xv[r].x, w0.y, acc[r][1]);
        acc[r][2] = fmaf(xv[r].x, w0.z, acc[r][2]);
        acc[r][3] = fmaf(xv[r].x, w0.w, acc[r][3]);
        acc[r][0] = fmaf(xv[r].y, w1.x, acc[r][0]);
        acc[r][1] = fmaf(xv[r].y, w1.y, acc[r][1]);
        acc[r][2] = fmaf(xv[r].y, w1.z, acc[r][2]);
        acc[r][3] = fmaf(xv[r].y, w1.w, acc[r][3]);
        acc[r][0] = fmaf(xv[r].z, w2.x, acc[r][0]);
        acc[r][1] = fmaf(xv[r].z, w2.y, acc[r][1]);
        acc[r][2] = fmaf(xv[r].z, w2.z, acc[r][2]);
        acc[r][3] = fmaf(xv[r].z, w2.w, acc[r][3]);
        acc[r][0] = fmaf(xv[r].w, w3.x, acc[r][0]);
        acc[r][1] = fmaf(xv[r].w, w3.y, acc[r][1]);
        acc[r][2] = fmaf(xv[r].w, w3.z, acc[r][2]);
        acc[r][3] = fmaf(xv[r].w, w3.w, acc[r][3]);
      }
    }
  }

  float4 asv = *(const float4*)(a_s + c0);
  float4 adv = *(const float4*)(a_d + c0);

#pragma unroll
  for (int r = 0; r < RPT; ++r) {
    long m = row0 + (long)rg * RPT + r;
    bool ok = m < M;
    if (ok) {
      ushort4 o;
      o.x = f2bf(acc[r][0]); o.y = f2bf(acc[r][1]);
      o.z = f2bf(acc[r][2]); o.w = f2bf(acc[r][3]);
      *(ushort4*)(Y + m * 256 + c0) = o;
    }
    float s = acc[r][0] * asv.x + acc[r][1] * asv.y + acc[r][2] * asv.z + acc[r][3] * asv.w;
    s += __shfl_xor(s, 1); s += __shfl_xor(s, 2);
    s += __shfl_xor(s, 4); s += __shfl_xor(s, 8);
    if (ok && (cg & 15) == 0) al_s[m * H + (c0 >> 6)] = s;
    float d = acc[r][0] * adv.x + acc[r][1] * adv.y + acc[r][2] * adv.z + acc[r][3] * adv.w;
    d += __shfl_xor(d, 1); d += __shfl_xor(d, 2);
    d += __shfl_xor(d, 4); d += __shfl_xor(d, 8);
    if (ok && (cg & 15) == 0) al_d[m * H + (c0 >> 6)] = d;
  }
}

__global__ __launch_bounds__(256) void proj_kernel(
    XSrc xsrc, int M, int K,
    const float* __restrict__ W,
    const float* __restrict__ a_s, const float* __restrict__ a_d,
    float* __restrict__ al_s, float* __restrict__ al_d,
    unsigned short* __restrict__ Y) {
  __shared__ float wl[16 * 256];
  __shared__ float xl[32 * 20];
  proj256_body(xsrc, M, K, W, a_s, a_d, al_s, al_d, Y, blockIdx.x, wl, xl);
}

// ---------------------------------------------------------------------------
// L4: edge scatter (3 graphs) + sg0 proj256 + sl proj64 + bp_Wd proj64,
// all mutually independent, one launch.  LDS ~21 KB -> 7 blocks/CU.
// ---------------------------------------------------------------------------
__global__ __launch_bounds__(256) void scatterproj_kernel(
    const int* r1, const int* c1, const float* e1, int E1, const int* p1, const int* cp1, const int* k1, int n1, int* s1, float* a1,
    const int* r2, const int* c2, const float* e2, int E2, const int* p2, const int* cp2, const int* k2, int n2, int* s2, float* a2,
    const int* r3, const int* c3, const float* e3, int E3, const int* p3, const int* cp3, const int* k3, int n3, int* s3, float* a3,
    PJob jsl, PJob jbp,
    XSrc xs0, int M0, int K0, const float* W0, const float* as0, const float* ad0,
    float* alS0, float* alD0, unsigned short* Y0, int nb0, int nbsl) {
  __shared__ float wl[16 * 256];
  __shared__ float xl[32 * 36];
  const int NB_SC = (ESS + EBIP + ESP + 255) / 256;   // 3125
  int b = blockIdx.x, t = threadIdx.x;
  if (b < NB_SC) {
    int i = b * 256 + t;
    if (i >= E1 + E2 + E3) return;
    int p = (i >> 8) & 7;
    if (i < E1) {
      int d = c1[i];
      int pos = p1[d] + cp1[p * n1 + d] + k1[i];
      s1[pos] = r1[i]; a1[pos] = e1[i];
    } else if (i < E1 + E2) {
      int j = i - E1;
      int d = c2[j];
      int pos = p2[d] + cp2[p * n2 + d] + k2[j];
      s2[pos] = r2[j]; a2[pos] = e2[j];
    } else {
      int j = i - E1 - E2;
      int d = c3[j];
      int pos = p3[d] + cp3[p * n3 + d] + k3[j];
      s3[pos] = r3[j]; a3[pos] = e3[j];
    }
  } else if (b < NB_SC + nb0) {
    proj256_body(xs0, M0, K0, W0, as0, ad0, alS0, alD0, Y0, b - NB_SC, wl, xl);
  } else if (b < NB_SC + nb0 + nbsl) {
    proj64_body(jsl, b - NB_SC - nb0, wl, xl);
  } else {
    proj64_body(jbp, b - NB_SC - nb0 - nbsl, wl, xl);
  }
}

// ---------------------------------------------------------------------------
// Fused GAT layer, H=4 C=64, bf16 hs: one wave per node covers all heads.
// Cooperative 64-edge prefetch + 4-way online-softmax ILP.  Self-loop with
// fill_value='mean' computed INLINE from the running csr_ea sum (processed
// last — online softmax is order-independent).
// ---------------------------------------------------------------------------
__device__ __forceinline__ void fma4_bf(float4& a, float al, ushort4 u) {
  a.x = fmaf(al, bf2f(u.x), a.x); a.y = fmaf(al, bf2f(u.y), a.y);
  a.z = fmaf(al, bf2f(u.z), a.z); a.w = fmaf(al, bf2f(u.w), a.w);
}
__device__ __forceinline__ void scale4(float4& a, float s) {
  a.x *= s; a.y *= s; a.z *= s; a.w *= s;
}

struct OS4 { float m, d; float4 a; };
__device__ __forceinline__ void os4_init(OS4& o) {
  o.m = -INFINITY; o.d = 0.f; o.a = make_float4(0.f, 0.f, 0.f, 0.f);
}
__device__ __forceinline__ void os4_upd(OS4& o, float l, ushort4 u) {
  if (l > o.m) { float sc = __expf(o.m - l); o.d *= sc; scale4(o.a, sc); o.m = l; }
  float ex = __expf(l - o.m);
  o.d += ex; fma4_bf(o.a, ex, u);
}
__device__ __forceinline__ void os4_mrg(OS4& A, const OS4& B) {
  if (B.m == -INFINITY) return;
  if (A.m == -INFINITY) { A = B; return; }
  float M = fmaxf(A.m, B.m);
  float sA = __expf(A.m - M), sB = __expf(B.m - M);
  A.d = A.d * sA + B.d * sB;
  A.a.x = A.a.x * sA + B.a.x * sB;
  A.a.y = A.a.y * sA + B.a.y * sB;
  A.a.z = A.a.z * sA + B.a.z * sB;
  A.a.w = A.a.w * sA + B.a.w * sB;
  A.m = M;
}

template <bool SELFLOOP>
__device__ __forceinline__ float4 gat4_body(
    int n, int lane, const int* __restrict__ dptr, const int* __restrict__ csr_src,
    const float* __restrict__ csr_ea, const float* __restrict__ al_s,
    const float* __restrict__ al_d, const float* __restrict__ dote,
    const unsigned short* __restrict__ hs,
    int* lds_i, float* lds_l) {
  int h = lane >> 4;
  float4 ald4 = *(const float4*)(al_d + (long)n * 4);   // broadcast
  float4 de4 = *(const float4*)dote;                    // broadcast
  int e0 = dptr[n], e1 = dptr[n + 1];
  OS4 o0, o1, o2, o3;
  os4_init(o0); os4_init(o1); os4_init(o2); os4_init(o3);
  float easum = 0.f;
  for (int base = e0; base < e1; base += 64) {
    int m = min(64, e1 - base);
    if (lane < m) {
      int s = csr_src[base + lane];
      float ea = csr_ea[base + lane];
      easum += ea;
      float4 av = *(const float4*)(al_s + (long)s * 4);
      float4 lv;
      lv.x = lrelu(av.x + ald4.x + ea * de4.x);
      lv.y = lrelu(av.y + ald4.y + ea * de4.y);
      lv.z = lrelu(av.z + ald4.z + ea * de4.z);
      lv.w = lrelu(av.w + ald4.w + ea * de4.w);
      lds_i[lane] = s;
      *(float4*)(lds_l + lane * 4) = lv;
    }
    __builtin_amdgcn_wave_barrier();   // scheduling fence (no runtime cost)
    int j = 0;
    for (; j + 4 <= m; j += 4) {
      int s0 = lds_i[j], s1 = lds_i[j + 1], s2 = lds_i[j + 2], s3 = lds_i[j + 3];
      float l0 = lds_l[(j + 0) * 4 + h];
      float l1 = lds_l[(j + 1) * 4 + h];
      float l2 = lds_l[(j + 2) * 4 + h];
      float l3 = lds_l[(j + 3) * 4 + h];
      ushort4 u0 = *(const ushort4*)(hs + (long)s0 * 256 + lane * 4);
      ushort4 u1 = *(const ushort4*)(hs + (long)s1 * 256 + lane * 4);
      ushort4 u2 = *(const ushort4*)(hs + (long)s2 * 256 + lane * 4);
      ushort4 u3 = *(const ushort4*)(hs + (long)s3 * 256 + lane * 4);
      os4_upd(o0, l0, u0); os4_upd(o1, l1, u1);
      os4_upd(o2, l2, u2); os4_upd(o3, l3, u3);
    }
    for (; j < m; ++j) {
      int s0 = lds_i[j];
      float l0 = lds_l[j * 4 + h];
      ushort4 u0 = *(const ushort4*)(hs + (long)s0 * 256 + lane * 4);
      os4_upd(o0, l0, u0);
    }
    __builtin_amdgcn_wave_barrier();   // keep next chunk's writes after reads
  }
  if (SELFLOOP) {
    float tot = wave_red_sum(easum);
    int deg = e1 - e0;
    float lmean = tot / (float)max(deg, 1);
    float ab = (h & 1) ? ald4.y : ald4.x;
    float cd = (h & 1) ? ald4.w : ald4.z;
    float aldh = (h & 2) ? cd : ab;
    float db = (h & 1) ? de4.y : de4.x;
    float dc = (h & 1) ? de4.w : de4.z;
    float deh = (h & 2) ? dc : db;
    float l = lrelu(al_s[(long)n * 4 + h] + aldh + lmean * deh);
    ushort4 u = *(const ushort4*)(hs + (long)n * 256 + lane * 4);
    os4_upd(o0, l, u);
  }
  os4_mrg(o0, o1); os4_mrg(o2, o3); os4_mrg(o0, o2);
  float inv = 1.f / (o0.d + 1e-16f);
  scale4(o0.a, inv);
  float4 a0 = o0.a;
  a0.x += __shfl_xor(a0.x, 16); a0.y += __shfl_xor(a0.y, 16);
  a0.z += __shfl_xor(a0.z, 16); a0.w += __shfl_xor(a0.w, 16);
  a0.x += __shfl_xor(a0.x, 32); a0.y += __shfl_xor(a0.y, 32);
  a0.z += __shfl_xor(a0.z, 32); a0.w += __shfl_xor(a0.w, 32);
  return a0;
}

template <bool SELFLOOP>
__global__ __launch_bounds__(256) void gat4_fused(
    int Nd, const int* __restrict__ dptr, const int* __restrict__ csr_src,
    const float* __restrict__ csr_ea, const float* __restrict__ al_s,
    const float* __restrict__ al_d, const float* __restrict__ dote,
    const unsigned short* __restrict__ hs,
    const float* __restrict__ bias, float* __restrict__ out) {
  __shared__ int li[4 * 64];
  __shared__ float ll[4 * 256];
  int wave = threadIdx.x >> 6, lane = threadIdx.x & 63;
  int n = blockIdx.x * 4 + wave;
  if (n >= Nd) return;
  float4 a0 = gat4_body<SELFLOOP>(n, lane, dptr, csr_src, csr_ea, al_s, al_d,
                                  dote, hs, li + wave * 64, ll + wave * 256);
  if (lane < 16) {
    float4 b = *(const float4*)(bias + lane * 4);
    float4 o;
    o.x = fmaxf(a0.x * 0.25f + b.x, 0.f);
    o.y = fmaxf(a0.y * 0.25f + b.y, 0.f);
    o.z = fmaxf(a0.z * 0.25f + b.z, 0.f);
    o.w = fmaxf(a0.w * 0.25f + b.w, 0.f);
    *(float4*)(out + (long)n * 64 + lane * 4) = o;
  }
}

// sg1 GAT layer with the bipartite source projection (64x64 bp_Ws) and
// al_s-source reduction fused into the epilogue.  Writes fp32 hs rows + alSb.
__global__ __launch_bounds__(256) void gat4_bp(
    int Nd, const int* __restrict__ dptr, const int* __restrict__ csr_src,
    const float* __restrict__ csr_ea, const float* __restrict__ al_s,
    const float* __restrict__ al_d, const float* __restrict__ dote,
    const unsigned short* __restrict__ hs,
    const float* __restrict__ bias, const float* __restrict__ bpW,
    const float* __restrict__ bp_as, float* __restrict__ hsrc,
    float* __restrict__ alSb) {
  __shared__ float Wl[64 * 64];
  __shared__ int li[4 * 64];
  __shared__ float ll[4 * 256];
  int t = threadIdx.x;
  {
    const float4* ws = (const float4*)bpW;
    float4* wd = (float4*)Wl;
    wd[t] = ws[t]; wd[t + 256] = ws[t + 256];
    wd[t + 512] = ws[t + 512]; wd[t + 768] = ws[t + 768];
  }
  __syncthreads();   // no block barriers after this point
  int wave = t >> 6, lane = t & 63;
  int n = blockIdx.x * 4 + wave;
  if (n >= Nd) return;
  float4 a0 = gat4_body<true>(n, lane, dptr, csr_src, csr_ea, al_s, al_d,
                              dote, hs, li + wave * 64, ll + wave * 256);
  // h row (relu'd spatial feature) — replicated across the 4 head groups
  float4 b = *(const float4*)(bias + (lane & 15) * 4);
  float4 o;
  o.x = fmaxf(a0.x * 0.25f + b.x, 0.f);
  o.y = fmaxf(a0.y * 0.25f + b.y, 0.f);
  o.z = fmaxf(a0.z * 0.25f + b.z, 0.f);
  o.w = fmaxf(a0.w * 0.25f + b.w, 0.f);
  // hs_src[lane] = sum_k h[k] * bpW[k][lane]
  float accf = 0.f;
#pragma unroll
  for (int q = 0; q < 16; ++q) {
    float vx = __shfl(o.x, q), vy = __shfl(o.y, q);
    float vz = __shfl(o.z, q), vw = __shfl(o.w, q);
    accf = fmaf(vx, Wl[(4 * q + 0) * 64 + lane], accf);
    accf = fmaf(vy, Wl[(4 * q + 1) * 64 + lane], accf);
    accf = fmaf(vz, Wl[(4 * q + 2) * 64 + lane], accf);
    accf = fmaf(vw, Wl[(4 * q + 3) * 64 + lane], accf);
  }
  hsrc[(long)n * 64 + lane] = accf;
  float s = wave_red_sum(accf * bp_as[lane]);
  if (lane == 0) alSb[n] = s;
}

// last species GAT layer with the fc (64x64) + split/softplus epilogue fused.
__global__ __launch_bounds__(256) void gat4_fc(
    int Nd, const int* __restrict__ dptr, const int* __restrict__ csr_src,
    const float* __restrict__ csr_ea, const float* __restrict__ al_s,
    const float* __restrict__ al_d, const float* __restrict__ dote,
    const unsigned short* __restrict__ hs,
    const float* __restrict__ bias, const float* __restrict__ fcW,
    const float* __restrict__ fcb, float* __restrict__ meanO,
    float* __restrict__ stdO) {
  __shared__ float Wl[64 * 64];
  __shared__ int li[4 * 64];
  __shared__ float ll[4 * 256];
  int t = threadIdx.x;
  {
    const float4* ws = (const float4*)fcW;
    float4* wd = (float4*)Wl;
    wd[t] = ws[t]; wd[t + 256] = ws[t + 256];
    wd[t + 512] = ws[t + 512]; wd[t + 768] = ws[t + 768];
  }
  __syncthreads();   // no block barriers after this point
  int wave = t >> 6, lane = t & 63;
  int n = blockIdx.x * 4 + wave;
  if (n >= Nd) return;
  float4 a0 = gat4_body<true>(n, lane, dptr, csr_src, csr_ea, al_s, al_d,
                              dote, hs, li + wave * 64, ll + wave * 256);
  float4 b = *(const float4*)(bias + (lane & 15) * 4);
  float4 o;
  o.x = fmaxf(a0.x * 0.25f + b.x, 0.f);
  o.y = fmaxf(a0.y * 0.25f + b.y, 0.f);
  o.z = fmaxf(a0.z * 0.25f + b.z, 0.f);
  o.w = fmaxf(a0.w * 0.25f + b.w, 0.f);
  float accf = 0.f;
#pragma unroll
  for (int q = 0; q < 16; ++q) {
    float vx = __shfl(o.x, q), vy = __shfl(o.y, q);
    float vz = __shfl(o.z, q), vw = __shfl(o.w, q);
    accf = fmaf(vx, Wl[(4 * q + 0) * 64 + lane], accf);
    accf = fmaf(vy, Wl[(4 * q + 1) * 64 + lane], accf);
    accf = fmaf(vz, Wl[(4 * q + 2) * 64 + lane], accf);
    accf = fmaf(vw, Wl[(4 * q + 3) * 64 + lane], accf);
  }
  float v = accf + fcb[lane];
  if (lane < 32) {
    meanO[(long)n * 32 + lane] = v;
  } else {
    stdO[(long)n * 32 + (lane - 32)] =
        fmaxf(v, 0.f) + log1pf(__expf(-fabsf(v))) + 1e-6f;
  }
}

// Fused GAT layer, H=1 C=64, fp32 hs (bipartite): wave per node, lane=channel.
__device__ __forceinline__ void os1_upd(float& m, float& d, float& c, float l, float hv) {
  if (l > m) { float sc = __expf(m - l); d *= sc; c *= sc; m = l; }
  float ex = __expf(l - m);
  d += ex; c = fmaf(ex, hv, c);
}
__device__ __forceinline__ void os1_mrg(float& m0, float& d0, float& c0,
                                        float m1, float d1, float c1) {
  if (m1 == -INFINITY) return;
  if (m0 == -INFINITY) { m0 = m1; d0 = d1; c0 = c1; return; }
  float M = fmaxf(m0, m1);
  float sA = __expf(m0 - M), sB = __expf(m1 - M);
  d0 = d0 * sA + d1 * sB; c0 = c0 * sA + c1 * sB; m0 = M;
}

__global__ __launch_bounds__(256) void gat1_fused(
    int Nd, const int* __restrict__ dptr, const int* __restrict__ csr_src,
    const float* __restrict__ csr_ea, const float* __restrict__ al_s,
    const float* __restrict__ al_d, const float* __restrict__ dote,
    const float* __restrict__ hs, const float* __restrict__ bias,
    float* __restrict__ out) {
  int wave = threadIdx.x >> 6, lane = threadIdx.x & 63;
  int n = blockIdx.x * 4 + wave;
  if (n >= Nd) return;
  float ald = al_d[n];
  float de = dote[0];
  int e0 = dptr[n], e1 = dptr[n + 1];
  float m0 = -INFINITY, d0 = 0.f, c0 = 0.f;
  float m1 = -INFINITY, d1 = 0.f, c1 = 0.f;
  float m2 = -INFINITY, d2 = 0.f, c2 = 0.f;
  float m3 = -INFINITY, d3 = 0.f, c3 = 0.f;
  for (int base = e0; base < e1; base += 64) {
    int m = min(64, e1 - base);
    int sm = 0; float lm = 0.f;
    if (lane < m) {
      sm = csr_src[base + lane];
      float ea = csr_ea[base + lane];
      lm = lrelu(al_s[sm] + ald + ea * de);
    }
    int j = 0;
    for (; j + 4 <= m; j += 4) {
      int s0 = __shfl(sm, j), s1 = __shfl(sm, j + 1);
      int s2 = __shfl(sm, j + 2), s3 = __shfl(sm, j + 3);
      float l0 = __shfl(lm, j), l1 = __shfl(lm, j + 1);
      float l2 = __shfl(lm, j + 2), l3 = __shfl(lm, j + 3);
      float h0 = hs[(long)s0 * 64 + lane];
      float h1 = hs[(long)s1 * 64 + lane];
      float h2 = hs[(long)s2 * 64 + lane];
      float h3 = hs[(long)s3 * 64 + lane];
      os1_upd(m0, d0, c0, l0, h0); os1_upd(m1, d1, c1, l1, h1);
      os1_upd(m2, d2, c2, l2, h2); os1_upd(m3, d3, c3, l3, h3);
    }
    for (; j < m; ++j) {
      int s0 = __shfl(sm, j);
      float l0 = __shfl(lm, j);
      float h0 = hs[(long)s0 * 64 + lane];
      os1_upd(m0, d0, c0, l0, h0);
    }
  }
  os1_mrg(m0, d0, c0, m1, d1, c1);
  os1_mrg(m2, d2, c2, m3, d3, c3);
  os1_mrg(m0, d0, c0, m2, d2, c2);
  float o = c0 / (d0 + 1e-16f);
  out[(long)n * 64 + lane] = fmaxf(o + bias[lane], 0.f);
}

// ---------------------------------------------------------------------------
extern "C" void kernel_launch(void* const* d_in, const int* in_sizes, int n_in,
                              void* d_out, int out_size, void* d_ws, size_t ws_size,
                              hipStream_t stream) {
  const float* sp_mean = (const float*)d_in[0];
  const float* sp_std  = (const float*)d_in[1];
  const void*  nanmask = d_in[2];
  const float* sp_gen  = (const float*)d_in[3];
  const float* sp_phy  = (const float*)d_in[4];
  const float* spat_x  = (const float*)d_in[5];
  const float* spat_g  = (const float*)d_in[6];
  const int*   ss_ei   = (const int*)d_in[7];
  const float* ss_ea   = (const float*)d_in[8];
  const int*   bip_ei  = (const int*)d_in[9];
  const float* bip_ea  = (const float*)d_in[10];
  const int*   sp_ei   = (const int*)d_in[11];
  const float* sp_ea   = (const float*)d_in[12];
  const float* sg0_W = (const float*)d_in[13]; const float* sg0_as = (const float*)d_in[14];
  const float* sg0_ad = (const float*)d_in[15]; const float* sg0_ae = (const float*)d_in[16];
  const float* sg0_We = (const float*)d_in[17]; const float* sg0_b = (const float*)d_in[18];
  const float* sg1_W = (const float*)d_in[19]; const float* sg1_as = (const float*)d_in[20];
  const float* sg1_ad = (const float*)d_in[21]; const float* sg1_ae = (const float*)d_in[22];
  const float* sg1_We = (const float*)d_in[23]; const float* sg1_b = (const float*)d_in[24];
  const float* pg0_W = (const float*)d_in[25]; const float* pg0_as = (const float*)d_in[26];
  const float* pg0_ad = (const float*)d_in[27]; const float* pg0_ae = (const float*)d_in[28];
  const float* pg0_We = (const float*)d_in[29]; const float* pg0_b = (const float*)d_in[30];
  const float* pg1_W = (const float*)d_in[31]; const float* pg1_as = (const float*)d_in[32];
  const float* pg1_ad = (const float*)d_in[33]; const float* pg1_ae = (const float*)d_in[34];
  const float* pg1_We = (const float*)d_in[35]; const float* pg1_b = (const float*)d_in[36];
  const float* bp_Ws = (const float*)d_in[37]; const float* bp_Wd = (const float*)d_in[38];
  const float* bp_as = (const float*)d_in[39]; const float* bp_ad = (const float*)d_in[40];
  const float* bp_ae = (const float*)d_in[41]; const float* bp_We = (const float*)d_in[42];
  const float* bp_b  = (const float*)d_in[43];
  const float* sl_W  = (const float*)d_in[44]; const float* sl_b  = (const float*)d_in[45];
  const float* fc_W  = (const float*)d_in[46]; const float* fc_b  = (const float*)d_in[47];

  // ---- workspace layout ----
  char* wsb = (char*)d_ws;
  size_t off = 0;
  auto A = [&](size_t nbytes) -> void* {
    void* p = wsb + off;
    off += (nbytes + 255) & ~(size_t)255;
    return p;
  };
  // zero-initialized region: partition counters
  int* ss_cp = (int*)A((size_t)8 * NSPAT * 4);
  int* bp_cp = (int*)A((size_t)8 * NSP * 4);
  int* pp_cp = (int*)A((size_t)8 * NSP * 4);
  size_t zbytes = off;
  int*   ss_cnt = (int*)A((NSPAT + 1) * 4);
  int*   bp_cnt = (int*)A((NSP + 1) * 4);
  int*   pp_cnt = (int*)A((NSP + 1) * 4);
  float* dotes = (float*)A(5 * 4 * sizeof(float));
  float* alS   = (float*)A((size_t)NSP * 4 * 4);
  float* alD   = (float*)A((size_t)NSP * 4 * 4);
  float* alSb  = (float*)A((size_t)NSPAT * 4);
  float* alDb  = (float*)A((size_t)NSP * 4);
  float* spc96 = (float*)A((size_t)NSP * 96 * 4);
  float* sp_in = (float*)A((size_t)NSP * 64 * 4);
  float* h0    = (float*)A((size_t)NSPAT * 16 * 4);
  float* h_a   = (float*)A((size_t)NSPAT * 64 * 4);
  float* HS    = (float*)A((size_t)NSP * 256 * 4);   // bf16 hs rows
  float* sts   = (float*)A((size_t)NSP * 64 * 4);
  float* x1    = (float*)A((size_t)NSP * 64 * 4);
  int*   ss_ptr = (int*)A((NSPAT + 1) * 4);
  int*   ss_src = (int*)A((size_t)ESS * 4);
  float* ss_cea = (float*)A((size_t)ESS * 4);
  int*   ss_rnk = (int*)A((size_t)ESS * 4);
  int*   bp_ptr = (int*)A((NSP + 1) * 4);
  int*   bp_src = (int*)A((size_t)EBIP * 4);
  float* bp_cea = (float*)A((size_t)EBIP * 4);
  int*   bp_rnk = (int*)A((size_t)EBIP * 4);
  int*   pp_ptr = (int*)A((NSP + 1) * 4);
  int*   pp_src = (int*)A((size_t)ESP * 4);
  float* pp_cea = (float*)A((size_t)ESP * 4);
  int*   pp_rnk = (int*)A((size_t)ESP * 4);
  (void)ws_size; (void)in_sizes; (void)n_in; (void)out_size;

  const int TB = 256;
  hipMemsetAsync(wsb, 0, zbytes, stream);

  // ---- L1: count + dote + spc96/h0 prep ----
  {
    DoteArgs da{};
    da.We[0] = sg0_We; da.ae[0] = sg0_ae;
    da.We[1] = sg1_We; da.ae[1] = sg1_ae;
    da.We[2] = bp_We;  da.ae[2] = bp_ae;
    da.We[3] = pg0_We; da.ae[3] = pg0_ae;
    da.We[4] = pg1_We; da.ae[4] = pg1_ae;
    da.dotes = dotes;
    PrepArgs pa{ sp_mean, sp_std, nanmask, spat_x, spat_g, spc96, h0 };
    int nb = cdiv_host(ESS + EBIP + ESP, TB) + 5 +
             cdiv_host((long)NSP * 96 + (long)NSPAT * 16, TB);
    count3x_kernel<<<nb, TB, 0, stream>>>(
        ss_ei + ESS, ss_cp, ss_rnk, NSPAT, ESS,
        bip_ei + EBIP, bp_cp, bp_rnk, NSP, EBIP,
        sp_ei + ESP, pp_cp, pp_rnk, NSP, ESP,
        da, pa);
  }
  // ---- L2: merge;  L3: scan ----
  merge3_kernel<<<cdiv_host(NSPAT + NSP + NSP, TB), TB, 0, stream>>>(
      ss_cp, ss_cnt, NSPAT, bp_cp, bp_cnt, NSP, pp_cp, pp_cnt, NSP);
  scan3_kernel<<<3, 1024, 0, stream>>>(ss_cnt, NSPAT, ss_ptr, bp_cnt, NSP, bp_ptr, pp_cnt, NSP, pp_ptr);

  // ---- L4: scatter + sg0 proj + sl proj + bp_Wd proj (one launch) ----
  {
    PJob jsl{}; jsl.xs.p[0] = spc96; jsl.xs.w[0] = 96; jsl.xs.p[1] = sp_gen; jsl.xs.w[1] = 64;
    jsl.xs.p[2] = sp_phy; jsl.xs.w[2] = 128; jsl.xs.n = 3;
    jsl.M = NSP; jsl.K = 288; jsl.W = sl_W; jsl.bias = sl_b; jsl.mode = 1; jsl.Y = sp_in;
    PJob jbp{}; jbp.xs.p[0] = sp_gen; jbp.xs.w[0] = 64; jbp.xs.p[1] = sp_phy; jbp.xs.w[1] = 128;
    jbp.xs.n = 2;
    jbp.M = NSP; jbp.K = 192; jbp.W = bp_Wd; jbp.mode = 0; jbp.a_d = bp_ad; jbp.al_d = alDb;
    XSrc xs0{}; xs0.p[0] = h0; xs0.w[0] = 16; xs0.n = 1;
    int nb_sc = cdiv_host(ESS + EBIP + ESP, TB);      // 3125
    int nb0 = cdiv_host(NSPAT, 32);                   // 313
    int nbsl = cdiv_host(NSP, 32);                    // 625
    int nbbp = cdiv_host(NSP, 32);                    // 625
    scatterproj_kernel<<<nb_sc + nb0 + nbsl + nbbp, TB, 0, stream>>>(
        ss_ei, ss_ei + ESS, ss_ea, ESS, ss_ptr, ss_cp, ss_rnk, NSPAT, ss_src, ss_cea,
        bip_ei, bip_ei + EBIP, bip_ea, EBIP, bp_ptr, bp_cp, bp_rnk, NSP, bp_src, bp_cea,
        sp_ei, sp_ei + ESP, sp_ea, ESP, pp_ptr, pp_cp, pp_rnk, NSP, pp_src, pp_cea,
        jsl, jbp,
        xs0, NSPAT, 16, sg0_W, sg0_as, sg0_ad, alS, alD, (unsigned short*)HS,
        nb0, nbsl);
  }

  // ---- spatial GNN ----
  gat4_fused<true><<<cdiv_host(NSPAT, 4), TB, 0, stream>>>(
      NSPAT, ss_ptr, ss_src, ss_cea, alS, alD, dotes + 0,
      (const unsigned short*)HS, sg0_b, h_a);
  {
    XSrc xs{}; xs.p[0] = h_a; xs.w[0] = 64; xs.n = 1;
    proj_kernel<<<cdiv_host(NSPAT, 32), TB, 0, stream>>>(xs, NSPAT, 64, sg1_W,
        sg1_as, sg1_ad, alS, alD, (unsigned short*)HS);
  }
  // sg1 GAT + fused bp_Ws source projection -> h_a (fp32 hs rows) + alSb
  gat4_bp<<<cdiv_host(NSPAT, 4), TB, 0, stream>>>(
      NSPAT, ss_ptr, ss_src, ss_cea, alS, alD, dotes + 4,
      (const unsigned short*)HS, sg1_b, bp_Ws, bp_as, h_a, alSb);

  // ---- bipartite GAT (spatial -> species), H=1, concat ----
  gat1_fused<<<cdiv_host(NSP, 4), TB, 0, stream>>>(
      NSP, bp_ptr, bp_src, bp_cea, alSb, alDb, dotes + 8, h_a, bp_b, sts);

  // ---- species GNN ----
  {
    XSrc xs{}; xs.p[0] = sts; xs.w[0] = 64; xs.p[1] = sp_in; xs.w[1] = 64; xs.n = 2;
    proj_kernel<<<cdiv_host(NSP, 32), TB, 0, stream>>>(xs, NSP, 128, pg0_W,
        pg0_as, pg0_ad, alS, alD, (unsigned short*)HS);
  }
  gat4_fused<true><<<cdiv_host(NSP, 4), TB, 0, stream>>>(
      NSP, pp_ptr, pp_src, pp_cea, alS, alD, dotes + 12,
      (const unsigned short*)HS, pg0_b, x1);
  {
    XSrc xs{}; xs.p[0] = x1; xs.w[0] = 64; xs.n = 1;
    proj_kernel<<<cdiv_host(NSP, 32), TB, 0, stream>>>(xs, NSP, 64, pg1_W,
        pg1_as, pg1_ad, alS, alD, (unsigned short*)HS);
  }
  // last GAT layer with fc + split/softplus fused — writes d_out directly
  gat4_fc<<<cdiv_host(NSP, 4), TB, 0, stream>>>(
      NSP, pp_ptr, pp_src, pp_cea, alS, alD, dotes + 16,
      (const unsigned short*)HS, pg1_b, fc_W, fc_b,
      (float*)d_out, (float*)d_out + (long)NSP * 32);
}

// Round 8
// 448.414 us; speedup vs baseline: 1.0145x; 1.0145x over previous
//
#include <hip/hip_runtime.h>
#include <hip/hip_bf16.h>

#define NSP   20000
#define NSPAT 10000
#define ESS   160000
#define EBIP  320000
#define ESP   320000

static inline int cdiv_host(long a, long b) { return (int)((a + b - 1) / b); }

__device__ __forceinline__ float wave_red_sum(float p) {
#pragma unroll
  for (int m = 32; m >= 1; m >>= 1) p += __shfl_xor(p, m, 64);
  return p;
}
__device__ __forceinline__ float bf2f(unsigned short u) {
  return __uint_as_float(((unsigned int)u) << 16);
}
__device__ __forceinline__ unsigned short f2bf(float f) {
  unsigned int u = __float_as_uint(f);
  unsigned int r = (u + 0x7FFF + ((u >> 16) & 1)) >> 16;  // RN-even
  return (unsigned short)r;
}
__device__ __forceinline__ float lrelu(float x) {
  return (x > 0.f) ? x : 0.2f * x;
}

struct DoteArgs { const float* We[5]; const float* ae[5]; float* dotes; };
struct PrepArgs {
  const float* mean; const float* stdv; const void* mask;
  const float* sx; const float* sg; float* spc96; float* h0;
};

// ---------------------------------------------------------------------------
// L1: CSR count (8-way partitioned atomics, [p][n] layout) + dote dot-products
// + spc96/h0 prep, one launch.
// ---------------------------------------------------------------------------
__global__ void count3x_kernel(
    const int* c1, int* cp1, int* rnk1, int n1, int E1,
    const int* c2, int* cp2, int* rnk2, int n2, int E2,
    const int* c3, int* cp3, int* rnk3, int n3, int E3,
    DoteArgs da, PrepArgs pa) {
  const int NB_E = (ESS + EBIP + ESP + 255) / 256;   // 3125
  int b = blockIdx.x, t = threadIdx.x;
  if (b < NB_E) {
    int i = b * 256 + t;
    if (i >= E1 + E2 + E3) return;
    int p = (i >> 8) & 7;
    if (i < E1) {
      int d = c1[i];
      rnk1[i] = atomicAdd(&cp1[p * n1 + d], 1);
    } else if (i < E1 + E2) {
      int j = i - E1;
      int d = c2[j];
      rnk2[j] = atomicAdd(&cp2[p * n2 + d], 1);
    } else {
      int j = i - E1 - E2;
      int d = c3[j];
      rnk3[j] = atomicAdd(&cp3[p * n3 + d], 1);
    }
  } else if (b < NB_E + 5) {
    int lb = b - NB_E;
    int n = (lb == 2) ? 64 : 256;
    if (t < n) {
      float p = wave_red_sum(da.We[lb][t] * da.ae[lb][t]);
      if ((t & 63) == 0) da.dotes[lb * 4 + (t >> 6)] = p;
    }
  } else {
    // prep blocks: per-block mask-format detect (reads 1KB broadcast)
    __shared__ int sflag;
    if (t < 64) {
      const unsigned int* mw = (const unsigned int*)pa.mask;
      unsigned int w0 = mw[t], w1 = mw[t + 64], w2 = mw[t + 128], w3 = mw[t + 192];
      bool ai = (w0 <= 1u) && (w1 <= 1u) && (w2 <= 1u) && (w3 <= 1u);
      auto okf = [](unsigned int w) { return w == 0u || w == 0x3f800000u; };
      bool af = okf(w0) && okf(w1) && okf(w2) && okf(w3);
      unsigned long long bi = __ballot(ai), bf = __ballot(af);
      if (t == 0) sflag = (bi == ~0ull) ? 0 : ((bf == ~0ull) ? 2 : 1);
    }
    __syncthreads();
    int mode = sflag;
    const long totA = (long)NSP * 96;
    const long totB = (long)NSPAT * 16;
    long i = (long)(b - NB_E - 5) * 256 + t;
    if (i >= totA + totB) return;
    if (i < totA) {
      int n = (int)(i / 96), c = (int)(i % 96);
      float v;
      if (c < 32) v = pa.mean[(long)n * 32 + c];
      else if (c < 64) v = pa.stdv[(long)n * 32 + (c - 32)];
      else {
        long j = (long)n * 32 + (c - 64);
        int mv;
        if (mode == 0) mv = ((const int*)pa.mask)[j];
        else if (mode == 2) mv = (((const float*)pa.mask)[j] != 0.0f);
        else mv = (int)((const unsigned char*)pa.mask)[j];
        v = mv ? 0.f : 1.f;   // vis = ~mask
      }
      pa.spc96[i] = v;
    } else {
      long k = i - totA;
      int n = (int)(k / 16), c = (int)(k % 16);
      pa.h0[k] = (c < 12) ? pa.sx[(long)n * 12 + c] : pa.sg[(long)n * 4 + (c - 12)];
    }
  }
}

// L2: per-node partition merge (coalesced per partition)
__global__ void merge3_kernel(int* cp1, int* c1, int n1,
                              int* cp2, int* c2, int n2,
                              int* cp3, int* c3, int n3) {
  int i = blockIdx.x * blockDim.x + threadIdx.x;
  int total = n1 + n2 + n3;
  if (i >= total) return;
  int *cp, *c; int n, d;
  if (i < n1) { cp = cp1; c = c1; n = n1; d = i; }
  else if (i < n1 + n2) { cp = cp2; c = c2; n = n2; d = i - n1; }
  else { cp = cp3; c = c3; n = n3; d = i - n1 - n2; }
  int s = 0;
#pragma unroll
  for (int p = 0; p < 8; ++p) { int t = cp[p * n + d]; cp[p * n + d] = s; s += t; }
  c[d] = s;
}

// L3: three block-wide exclusive scans
__global__ __launch_bounds__(1024) void scan3_kernel(
    const int* cntA, int nA, int* ptrA,
    const int* cntB, int nB, int* ptrB,
    const int* cntC, int nC, int* ptrC) {
  const int* cnt; int n; int* ptr;
  if (blockIdx.x == 0) { cnt = cntA; n = nA; ptr = ptrA; }
  else if (blockIdx.x == 1) { cnt = cntB; n = nB; ptr = ptrB; }
  else { cnt = cntC; n = nC; ptr = ptrC; }
  __shared__ int part[1024];
  int t = threadIdx.x;
  int ch = (n + 1023) / 1024;
  int beg = t * ch, end = min(beg + ch, n);
  int s = 0;
  for (int i = beg; i < end; ++i) s += cnt[i];
  part[t] = s;
  __syncthreads();
  for (int off = 1; off < 1024; off <<= 1) {
    int v = (t >= off) ? part[t - off] : 0;
    __syncthreads();
    part[t] += v;
    __syncthreads();
  }
  int run = (t == 0) ? 0 : part[t - 1];
  for (int i = beg; i < end; ++i) { ptr[i] = run; run += cnt[i]; }
  if (t == 1023) ptr[n] = part[1023];
}

struct XSrc { const float* p[5]; int w[5]; int n; };
struct PJob {
  XSrc xs; int M, K;
  const float* W; const float* bias; int mode;
  const float* a_s; const float* a_d;
  float* al_s; float* al_d;
  float* Y; float* Y2;
};

// ---------------------------------------------------------------------------
// NOUT=64 projection body, tiled: BR=32 rows/block, KC=32.  4 cols x 2 rows.
// mode: 0 plain (skip store if Y null), 1 bias+relu, 2 final split.
// ---------------------------------------------------------------------------
__device__ __forceinline__ void proj64_body(const PJob& J, int bid,
                                            float* wl, float* xl) {
  constexpr int KC = 32;
  constexpr int BR = 32;
  constexpr int KCP = 36;
  int t = threadIdx.x;
  long row0 = (long)bid * BR;
  if (row0 >= J.M) return;
  int cg = t & 15, rg = t >> 4;
  int c0 = cg * 4;

  float acc[2][4];
#pragma unroll
  for (int r = 0; r < 2; ++r)
#pragma unroll
    for (int j = 0; j < 4; ++j) acc[r][j] = 0.f;

  for (int k0 = 0; k0 < J.K; k0 += KC) {
    int seg = 0; int base = 0;
    while (k0 >= base + J.xs.w[seg]) { base += J.xs.w[seg]; ++seg; }
    const float* Xp = J.xs.p[seg];
    int stride = J.xs.w[seg];
    int kloc = k0 - base;

    __syncthreads();
    {
      const float4* ws = (const float4*)(J.W + (long)k0 * 64);
      float4* wd = (float4*)wl;
      wd[t] = ws[t];
      wd[t + 256] = ws[t + 256];
    }
    {
      int r = t >> 3, kq = (t & 7) * 4;
      long rr = row0 + r; if (rr >= J.M) rr = J.M - 1;
      float4 v = *(const float4*)(Xp + rr * stride + kloc + kq);
      *(float4*)(xl + r * KCP + kq) = v;
    }
    __syncthreads();

    for (int kg = 0; kg < KC; kg += 4) {
      float4 w0 = *(const float4*)(wl + (kg + 0) * 64 + c0);
      float4 w1 = *(const float4*)(wl + (kg + 1) * 64 + c0);
      float4 w2 = *(const float4*)(wl + (kg + 2) * 64 + c0);
      float4 w3 = *(const float4*)(wl + (kg + 3) * 64 + c0);
#pragma unroll
      for (int r = 0; r < 2; ++r) {
        float4 xv = *(const float4*)(xl + (rg * 2 + r) * KCP + kg);
        acc[r][0] = fmaf(xv.x, w0.x, acc[r][0]);
        acc[r][1] = fmaf(xv.x, w0.y, acc[r][1]);
        acc[r][2] = fmaf(xv.x, w0.z, acc[r][2]);
        acc[r][3] = fmaf(xv.x, w0.w, acc[r][3]);
        acc[r][0] = fmaf(xv.y, w1.x, acc[r][0]);
        acc[r][1] = fmaf(xv.y, w1.y, acc[r][1]);
        acc[r][2] = fmaf(xv.y, w1.z, acc[r][2]);
        acc[r][3] = fmaf(xv.y, w1.w, acc[r][3]);
        acc[r][0] = fmaf(xv.z, w2.x, acc[r][0]);
        acc[r][1] = fmaf(xv.z, w2.y, acc[r][1]);
        acc[r][2] = fmaf(xv.z, w2.z, acc[r][2]);
        acc[r][3] = fmaf(xv.z, w2.w, acc[r][3]);
        acc[r][0] = fmaf(xv.w, w3.x, acc[r][0]);
        acc[r][1] = fmaf(xv.w, w3.y, acc[r][1]);
        acc[r][2] = fmaf(xv.w, w3.z, acc[r][2]);
        acc[r][3] = fmaf(xv.w, w3.w, acc[r][3]);
      }
    }
  }

  float4 bv = make_float4(0.f, 0.f, 0.f, 0.f);
  float4 asv = make_float4(0.f, 0.f, 0.f, 0.f);
  float4 adv = make_float4(0.f, 0.f, 0.f, 0.f);
  if (J.bias) bv = *(const float4*)(J.bias + c0);
  if (J.a_s) asv = *(const float4*)(J.a_s + c0);
  if (J.a_d) adv = *(const float4*)(J.a_d + c0);

#pragma unroll
  for (int r = 0; r < 2; ++r) {
    long m = row0 + rg * 2 + r;
    bool ok = m < J.M;
    float v0 = acc[r][0] + bv.x, v1 = acc[r][1] + bv.y;
    float v2 = acc[r][2] + bv.z, v3 = acc[r][3] + bv.w;
    if (J.mode == 1) {
      if (ok)
        *(float4*)(J.Y + m * 64 + c0) = make_float4(
            fmaxf(v0, 0.f), fmaxf(v1, 0.f), fmaxf(v2, 0.f), fmaxf(v3, 0.f));
    } else if (J.mode == 2) {
      if (ok) {
        if (c0 < 32) {
          *(float4*)(J.Y + m * 32 + c0) = make_float4(v0, v1, v2, v3);
        } else {
          float4 o;
          o.x = fmaxf(v0, 0.f) + log1pf(__expf(-fabsf(v0))) + 1e-6f;
          o.y = fmaxf(v1, 0.f) + log1pf(__expf(-fabsf(v1))) + 1e-6f;
          o.z = fmaxf(v2, 0.f) + log1pf(__expf(-fabsf(v2))) + 1e-6f;
          o.w = fmaxf(v3, 0.f) + log1pf(__expf(-fabsf(v3))) + 1e-6f;
          *(float4*)(J.Y2 + m * 32 + (c0 - 32)) = o;
        }
      }
    } else if (ok && J.Y) {
      *(float4*)(J.Y + m * 64 + c0) = make_float4(v0, v1, v2, v3);
    }
    if (J.a_s) {
      float s = acc[r][0] * asv.x + acc[r][1] * asv.y + acc[r][2] * asv.z + acc[r][3] * asv.w;
      s += __shfl_xor(s, 1); s += __shfl_xor(s, 2);
      s += __shfl_xor(s, 4); s += __shfl_xor(s, 8);
      if (ok && cg == 0) J.al_s[m] = s;
    }
    if (J.a_d) {
      float s = acc[r][0] * adv.x + acc[r][1] * adv.y + acc[r][2] * adv.z + acc[r][3] * adv.w;
      s += __shfl_xor(s, 1); s += __shfl_xor(s, 2);
      s += __shfl_xor(s, 4); s += __shfl_xor(s, 8);
      if (ok && cg == 0) J.al_d[m] = s;
    }
  }
}

// ---------------------------------------------------------------------------
// NOUT=256 projection body (tiled, BR=32, KC=32): X and W staged in LDS.
// bf16 out.
// ---------------------------------------------------------------------------
__device__ __forceinline__ void proj256_body(
    const XSrc& xsrc, int M, int K,
    const float* __restrict__ W,
    const float* __restrict__ a_s, const float* __restrict__ a_d,
    float* __restrict__ al_s, float* __restrict__ al_d,
    unsigned short* __restrict__ Y, int bid, float* wl, float* xl) {
  constexpr int KC = 32;
  constexpr int RPT = 8;
  constexpr int BR = 32;
  constexpr int KCP = 36;
  constexpr int H = 4;
  int t = threadIdx.x;
  int cg = t & 63, rg = t >> 6;
  int c0 = cg * 4;
  long row0 = (long)bid * BR;
  if (row0 >= M) return;

  float acc[RPT][4];
#pragma unroll
  for (int r = 0; r < RPT; ++r)
#pragma unroll
    for (int j = 0; j < 4; ++j) acc[r][j] = 0.f;

  for (int k0 = 0; k0 < K; k0 += KC) {
    int kc = min(KC, K - k0);
    int seg = 0; int base = 0;
    while (k0 >= base + xsrc.w[seg]) { base += xsrc.w[seg]; ++seg; }
    const float* Xp = xsrc.p[seg];
    int stride = xsrc.w[seg];
    int kloc = k0 - base;

    __syncthreads();
    {
      const float4* wsrc = (const float4*)(W + (long)k0 * 256);
      float4* wdst = (float4*)wl;
      for (int i = t; i < (kc * 256) >> 2; i += 256) wdst[i] = wsrc[i];
    }
    for (int i = t; i < BR * 8; i += 256) {
      int r = i >> 3, kq = (i & 7) * 4;
      if (kq < kc) {
        long rr = row0 + r; if (rr >= M) rr = M - 1;
        float4 v = *(const float4*)(Xp + rr * stride + kloc + kq);
        *(float4*)(xl + r * KCP + kq) = v;
      }
    }
    __syncthreads();

    for (int kg = 0; kg < kc; kg += 4) {
      float4 w0 = *(const float4*)(wl + (kg + 0) * 256 + c0);
      float4 w1 = *(const float4*)(wl + (kg + 1) * 256 + c0);
      float4 w2 = *(const float4*)(wl + (kg + 2) * 256 + c0);
      float4 w3 = *(const float4*)(wl + (kg + 3) * 256 + c0);
      float4 xv[RPT];
#pragma unroll
      for (int r = 0; r < RPT; ++r)
        xv[r] = *(const float4*)(xl + (rg * RPT + r) * KCP + kg);
#pragma unroll
      for (int r = 0; r < RPT; ++r) {
        acc[r][0] = fmaf(xv[r].x, w0.x, acc[r][0]);
        acc[r][1] = fmaf(xv[r].x, w0.y, acc[r][1]);
        acc[r][2] = fmaf(xv[r].x, w0.z, acc[r][2]);
        acc[r][3] = fmaf(xv[r].x, w0.w, acc[r][3]);
        acc[r][0] = fmaf(xv[r].y, w1.x, acc[r][0]);
        acc[r][1] = fmaf(xv[r].y, w1.y, acc[r][1]);
        acc[r][2] = fmaf(xv[r].y, w1.z, acc[r][2]);
        acc[r][3] = fmaf(xv[r].y, w1.w, acc[r][3]);
        acc[r][0] = fmaf(xv[r].z, w2.x, acc[r][0]);
        acc[r][1] = fmaf(xv[r].z, w2.y, acc[r][1]);
        acc[r][2] = fmaf(xv[r].z, w2.z, acc[r][2]);
        acc[r][3] = fmaf(xv[r].z, w2.w, acc[r][3]);
        acc[r][0] = fmaf(xv[r].w, w3.x, acc[r][0]);
        acc[r][1] = fmaf(xv[r].w, w3.y, acc[r][1]);
        acc[r][2] = fmaf(xv[r].w, w3.z, acc[r][2]);
        acc[r][3] = fmaf(xv[r].w, w3.w, acc[r][3]);
      }
    }
  }

  float4 asv = *(const float4*)(a_s + c0);
  float4 adv = *(const float4*)(a_d + c0);

#pragma unroll
  for (int r = 0; r < RPT; ++r) {
    long m = row0 + (long)rg * RPT + r;
    bool ok = m < M;
    if (ok) {
      ushort4 o;
      o.x = f2bf(acc[r][0]); o.y = f2bf(acc[r][1]);
      o.z = f2bf(acc[r][2]); o.w = f2bf(acc[r][3]);
      *(ushort4*)(Y + m * 256 + c0) = o;
    }
    float s = acc[r][0] * asv.x + acc[r][1] * asv.y + acc[r][2] * asv.z + acc[r][3] * asv.w;
    s += __shfl_xor(s, 1); s += __shfl_xor(s, 2);
    s += __shfl_xor(s, 4); s += __shfl_xor(s, 8);
    if (ok && (cg & 15) == 0) al_s[m * H + (c0 >> 6)] = s;
    float d = acc[r][0] * adv.x + acc[r][1] * adv.y + acc[r][2] * adv.z + acc[r][3] * adv.w;
    d += __shfl_xor(d, 1); d += __shfl_xor(d, 2);
    d += __shfl_xor(d, 4); d += __shfl_xor(d, 8);
    if (ok && (cg & 15) == 0) al_d[m * H + (c0 >> 6)] = d;
  }
}

__global__ __launch_bounds__(256) void proj_kernel(
    XSrc xsrc, int M, int K,
    const float* __restrict__ W,
    const float* __restrict__ a_s, const float* __restrict__ a_d,
    float* __restrict__ al_s, float* __restrict__ al_d,
    unsigned short* __restrict__ Y) {
  __shared__ float wl[32 * 256];
  __shared__ float xl[32 * 36];
  proj256_body(xsrc, M, K, W, a_s, a_d, al_s, al_d, Y, blockIdx.x, wl, xl);
}

// ---------------------------------------------------------------------------
// L4: edge scatter (3 graphs, interleaved int2 {src, ea} CSR payload) +
// sg0 proj256 + sl proj64 + bp_Wd proj64, one launch.
// ---------------------------------------------------------------------------
__global__ __launch_bounds__(256) void scatterproj_kernel(
    const int* r1, const int* c1, const float* e1, int E1, const int* p1, const int* cp1, const int* k1, int n1, int2* se1,
    const int* r2, const int* c2, const float* e2, int E2, const int* p2, const int* cp2, const int* k2, int n2, int2* se2,
    const int* r3, const int* c3, const float* e3, int E3, const int* p3, const int* cp3, const int* k3, int n3, int2* se3,
    PJob jsl, PJob jbp,
    XSrc xs0, int M0, int K0, const float* W0, const float* as0, const float* ad0,
    float* alS0, float* alD0, unsigned short* Y0, int nb0, int nbsl) {
  __shared__ float wl[32 * 256];
  __shared__ float xl[32 * 36];
  const int NB_SC = (ESS + EBIP + ESP + 255) / 256;   // 3125
  int b = blockIdx.x, t = threadIdx.x;
  if (b < NB_SC) {
    int i = b * 256 + t;
    if (i >= E1 + E2 + E3) return;
    int p = (i >> 8) & 7;
    if (i < E1) {
      int d = c1[i];
      int pos = p1[d] + cp1[p * n1 + d] + k1[i];
      se1[pos] = make_int2(r1[i], __float_as_int(e1[i]));
    } else if (i < E1 + E2) {
      int j = i - E1;
      int d = c2[j];
      int pos = p2[d] + cp2[p * n2 + d] + k2[j];
      se2[pos] = make_int2(r2[j], __float_as_int(e2[j]));
    } else {
      int j = i - E1 - E2;
      int d = c3[j];
      int pos = p3[d] + cp3[p * n3 + d] + k3[j];
      se3[pos] = make_int2(r3[j], __float_as_int(e3[j]));
    }
  } else if (b < NB_SC + nb0) {
    proj256_body(xs0, M0, K0, W0, as0, ad0, alS0, alD0, Y0, b - NB_SC, wl, xl);
  } else if (b < NB_SC + nb0 + nbsl) {
    proj64_body(jsl, b - NB_SC - nb0, wl, xl);
  } else {
    proj64_body(jbp, b - NB_SC - nb0 - nbsl, wl, xl);
  }
}

// ---------------------------------------------------------------------------
// Fused GAT layer, H=4 C=64, bf16 hs: one wave per node covers all heads.
// Cooperative 64-edge prefetch (one int2 load/edge) + 8 gathers in flight on
// 4 online-softmax streams (per-stream edge order unchanged).  Self-loop
// 'mean' edge-attr computed inline from the running csr ea sum.
// ---------------------------------------------------------------------------
__device__ __forceinline__ void fma4_bf(float4& a, float al, ushort4 u) {
  a.x = fmaf(al, bf2f(u.x), a.x); a.y = fmaf(al, bf2f(u.y), a.y);
  a.z = fmaf(al, bf2f(u.z), a.z); a.w = fmaf(al, bf2f(u.w), a.w);
}
__device__ __forceinline__ void scale4(float4& a, float s) {
  a.x *= s; a.y *= s; a.z *= s; a.w *= s;
}

struct OS4 { float m, d; float4 a; };
__device__ __forceinline__ void os4_init(OS4& o) {
  o.m = -INFINITY; o.d = 0.f; o.a = make_float4(0.f, 0.f, 0.f, 0.f);
}
__device__ __forceinline__ void os4_upd(OS4& o, float l, ushort4 u) {
  if (l > o.m) { float sc = __expf(o.m - l); o.d *= sc; scale4(o.a, sc); o.m = l; }
  float ex = __expf(l - o.m);
  o.d += ex; fma4_bf(o.a, ex, u);
}
__device__ __forceinline__ void os4_mrg(OS4& A, const OS4& B) {
  if (B.m == -INFINITY) return;
  if (A.m == -INFINITY) { A = B; return; }
  float M = fmaxf(A.m, B.m);
  float sA = __expf(A.m - M), sB = __expf(B.m - M);
  A.d = A.d * sA + B.d * sB;
  A.a.x = A.a.x * sA + B.a.x * sB;
  A.a.y = A.a.y * sA + B.a.y * sB;
  A.a.z = A.a.z * sA + B.a.z * sB;
  A.a.w = A.a.w * sA + B.a.w * sB;
  A.m = M;
}

template <bool SELFLOOP>
__device__ __forceinline__ float4 gat4_body(
    int n, int lane, const int* __restrict__ dptr, const int2* __restrict__ csr_se,
    const float* __restrict__ al_s,
    const float* __restrict__ al_d, const float* __restrict__ dote,
    const unsigned short* __restrict__ hs,
    int* lds_i, float* lds_l) {
  int h = lane >> 4;
  float4 ald4 = *(const float4*)(al_d + (long)n * 4);   // broadcast
  float4 de4 = *(const float4*)dote;                    // broadcast
  int e0 = dptr[n], e1 = dptr[n + 1];
  OS4 o0, o1, o2, o3;
  os4_init(o0); os4_init(o1); os4_init(o2); os4_init(o3);
  float easum = 0.f;
  for (int base = e0; base < e1; base += 64) {
    int m = min(64, e1 - base);
    if (lane < m) {
      int2 v = csr_se[base + lane];
      int s = v.x;
      float ea = __int_as_float(v.y);
      easum += ea;
      float4 av = *(const float4*)(al_s + (long)s * 4);
      float4 lv;
      lv.x = lrelu(av.x + ald4.x + ea * de4.x);
      lv.y = lrelu(av.y + ald4.y + ea * de4.y);
      lv.z = lrelu(av.z + ald4.z + ea * de4.z);
      lv.w = lrelu(av.w + ald4.w + ea * de4.w);
      lds_i[lane] = s;
      *(float4*)(lds_l + lane * 4) = lv;
    }
    __builtin_amdgcn_wave_barrier();   // scheduling fence (no runtime cost)
    int j = 0;
    for (; j + 8 <= m; j += 8) {
      int s0 = lds_i[j],     s1 = lds_i[j + 1], s2 = lds_i[j + 2], s3 = lds_i[j + 3];
      int s4 = lds_i[j + 4], s5 = lds_i[j + 5], s6 = lds_i[j + 6], s7 = lds_i[j + 7];
      float l0 = lds_l[(j + 0) * 4 + h], l1 = lds_l[(j + 1) * 4 + h];
      float l2 = lds_l[(j + 2) * 4 + h], l3 = lds_l[(j + 3) * 4 + h];
      float l4 = lds_l[(j + 4) * 4 + h], l5 = lds_l[(j + 5) * 4 + h];
      float l6 = lds_l[(j + 6) * 4 + h], l7 = lds_l[(j + 7) * 4 + h];
      ushort4 u0 = *(const ushort4*)(hs + (long)s0 * 256 + lane * 4);
      ushort4 u1 = *(const ushort4*)(hs + (long)s1 * 256 + lane * 4);
      ushort4 u2 = *(const ushort4*)(hs + (long)s2 * 256 + lane * 4);
      ushort4 u3 = *(const ushort4*)(hs + (long)s3 * 256 + lane * 4);
      ushort4 u4 = *(const ushort4*)(hs + (long)s4 * 256 + lane * 4);
      ushort4 u5 = *(const ushort4*)(hs + (long)s5 * 256 + lane * 4);
      ushort4 u6 = *(const ushort4*)(hs + (long)s6 * 256 + lane * 4);
      ushort4 u7 = *(const ushort4*)(hs + (long)s7 * 256 + lane * 4);
      os4_upd(o0, l0, u0); os4_upd(o1, l1, u1);
      os4_upd(o2, l2, u2); os4_upd(o3, l3, u3);
      os4_upd(o0, l4, u4); os4_upd(o1, l5, u5);
      os4_upd(o2, l6, u6); os4_upd(o3, l7, u7);
    }
    for (; j + 4 <= m; j += 4) {
      int s0 = lds_i[j], s1 = lds_i[j + 1], s2 = lds_i[j + 2], s3 = lds_i[j + 3];
      float l0 = lds_l[(j + 0) * 4 + h];
      float l1 = lds_l[(j + 1) * 4 + h];
      float l2 = lds_l[(j + 2) * 4 + h];
      float l3 = lds_l[(j + 3) * 4 + h];
      ushort4 u0 = *(const ushort4*)(hs + (long)s0 * 256 + lane * 4);
      ushort4 u1 = *(const ushort4*)(hs + (long)s1 * 256 + lane * 4);
      ushort4 u2 = *(const ushort4*)(hs + (long)s2 * 256 + lane * 4);
      ushort4 u3 = *(const ushort4*)(hs + (long)s3 * 256 + lane * 4);
      os4_upd(o0, l0, u0); os4_upd(o1, l1, u1);
      os4_upd(o2, l2, u2); os4_upd(o3, l3, u3);
    }
    for (; j < m; ++j) {
      int s0 = lds_i[j];
      float l0 = lds_l[j * 4 + h];
      ushort4 u0 = *(const ushort4*)(hs + (long)s0 * 256 + lane * 4);
      os4_upd(o0, l0, u0);
    }
    __builtin_amdgcn_wave_barrier();   // keep next chunk's writes after reads
  }
  if (SELFLOOP) {
    float tot = wave_red_sum(easum);
    int deg = e1 - e0;
    float lmean = tot / (float)max(deg, 1);
    float ab = (h & 1) ? ald4.y : ald4.x;
    float cd = (h & 1) ? ald4.w : ald4.z;
    float aldh = (h & 2) ? cd : ab;
    float db = (h & 1) ? de4.y : de4.x;
    float dc = (h & 1) ? de4.w : de4.z;
    float deh = (h & 2) ? dc : db;
    float l = lrelu(al_s[(long)n * 4 + h] + aldh + lmean * deh);
    ushort4 u = *(const ushort4*)(hs + (long)n * 256 + lane * 4);
    os4_upd(o0, l, u);
  }
  os4_mrg(o0, o1); os4_mrg(o2, o3); os4_mrg(o0, o2);
  float inv = 1.f / (o0.d + 1e-16f);
  scale4(o0.a, inv);
  float4 a0 = o0.a;
  a0.x += __shfl_xor(a0.x, 16); a0.y += __shfl_xor(a0.y, 16);
  a0.z += __shfl_xor(a0.z, 16); a0.w += __shfl_xor(a0.w, 16);
  a0.x += __shfl_xor(a0.x, 32); a0.y += __shfl_xor(a0.y, 32);
  a0.z += __shfl_xor(a0.z, 32); a0.w += __shfl_xor(a0.w, 32);
  return a0;
}

template <bool SELFLOOP>
__global__ __launch_bounds__(256) void gat4_fused(
    int Nd, const int* __restrict__ dptr, const int2* __restrict__ csr_se,
    const float* __restrict__ al_s,
    const float* __restrict__ al_d, const float* __restrict__ dote,
    const unsigned short* __restrict__ hs,
    const float* __restrict__ bias, float* __restrict__ out) {
  __shared__ int li[4 * 64];
  __shared__ float ll[4 * 256];
  int wave = threadIdx.x >> 6, lane = threadIdx.x & 63;
  int n = blockIdx.x * 4 + wave;
  if (n >= Nd) return;
  float4 a0 = gat4_body<SELFLOOP>(n, lane, dptr, csr_se, al_s, al_d,
                                  dote, hs, li + wave * 64, ll + wave * 256);
  if (lane < 16) {
    float4 b = *(const float4*)(bias + lane * 4);
    float4 o;
    o.x = fmaxf(a0.x * 0.25f + b.x, 0.f);
    o.y = fmaxf(a0.y * 0.25f + b.y, 0.f);
    o.z = fmaxf(a0.z * 0.25f + b.z, 0.f);
    o.w = fmaxf(a0.w * 0.25f + b.w, 0.f);
    *(float4*)(out + (long)n * 64 + lane * 4) = o;
  }
}

// sg1 GAT layer with the bipartite source projection (64x64 bp_Ws) and
// al_s-source reduction fused into the epilogue.  Writes fp32 hs rows + alSb.
__global__ __launch_bounds__(256) void gat4_bp(
    int Nd, const int* __restrict__ dptr, const int2* __restrict__ csr_se,
    const float* __restrict__ al_s,
    const float* __restrict__ al_d, const float* __restrict__ dote,
    const unsigned short* __restrict__ hs,
    const float* __restrict__ bias, const float* __restrict__ bpW,
    const float* __restrict__ bp_as, float* __restrict__ hsrc,
    float* __restrict__ alSb) {
  __shared__ float Wl[64 * 64];
  __shared__ int li[4 * 64];
  __shared__ float ll[4 * 256];
  int t = threadIdx.x;
  {
    const float4* ws = (const float4*)bpW;
    float4* wd = (float4*)Wl;
    wd[t] = ws[t]; wd[t + 256] = ws[t + 256];
    wd[t + 512] = ws[t + 512]; wd[t + 768] = ws[t + 768];
  }
  __syncthreads();   // no block barriers after this point
  int wave = t >> 6, lane = t & 63;
  int n = blockIdx.x * 4 + wave;
  if (n >= Nd) return;
  float4 a0 = gat4_body<true>(n, lane, dptr, csr_se, al_s, al_d,
                              dote, hs, li + wave * 64, ll + wave * 256);
  // h row (relu'd spatial feature) — replicated across the 4 head groups
  float4 b = *(const float4*)(bias + (lane & 15) * 4);
  float4 o;
  o.x = fmaxf(a0.x * 0.25f + b.x, 0.f);
  o.y = fmaxf(a0.y * 0.25f + b.y, 0.f);
  o.z = fmaxf(a0.z * 0.25f + b.z, 0.f);
  o.w = fmaxf(a0.w * 0.25f + b.w, 0.f);
  // hs_src[lane] = sum_k h[k] * bpW[k][lane]
  float accf = 0.f;
#pragma unroll
  for (int q = 0; q < 16; ++q) {
    float vx = __shfl(o.x, q), vy = __shfl(o.y, q);
    float vz = __shfl(o.z, q), vw = __shfl(o.w, q);
    accf = fmaf(vx, Wl[(4 * q + 0) * 64 + lane], accf);
    accf = fmaf(vy, Wl[(4 * q + 1) * 64 + lane], accf);
    accf = fmaf(vz, Wl[(4 * q + 2) * 64 + lane], accf);
    accf = fmaf(vw, Wl[(4 * q + 3) * 64 + lane], accf);
  }
  hsrc[(long)n * 64 + lane] = accf;
  float s = wave_red_sum(accf * bp_as[lane]);
  if (lane == 0) alSb[n] = s;
}

// last species GAT layer with the fc (64x64) + split/softplus epilogue fused.
__global__ __launch_bounds__(256) void gat4_fc(
    int Nd, const int* __restrict__ dptr, const int2* __restrict__ csr_se,
    const float* __restrict__ al_s,
    const float* __restrict__ al_d, const float* __restrict__ dote,
    const unsigned short* __restrict__ hs,
    const float* __restrict__ bias, const float* __restrict__ fcW,
    const float* __restrict__ fcb, float* __restrict__ meanO,
    float* __restrict__ stdO) {
  __shared__ float Wl[64 * 64];
  __shared__ int li[4 * 64];
  __shared__ float ll[4 * 256];
  int t = threadIdx.x;
  {
    const float4* ws = (const float4*)fcW;
    float4* wd = (float4*)Wl;
    wd[t] = ws[t]; wd[t + 256] = ws[t + 256];
    wd[t + 512] = ws[t + 512]; wd[t + 768] = ws[t + 768];
  }
  __syncthreads();   // no block barriers after this point
  int wave = t >> 6, lane = t & 63;
  int n = blockIdx.x * 4 + wave;
  if (n >= Nd) return;
  float4 a0 = gat4_body<true>(n, lane, dptr, csr_se, al_s, al_d,
                              dote, hs, li + wave * 64, ll + wave * 256);
  float4 b = *(const float4*)(bias + (lane & 15) * 4);
  float4 o;
  o.x = fmaxf(a0.x * 0.25f + b.x, 0.f);
  o.y = fmaxf(a0.y * 0.25f + b.y, 0.f);
  o.z = fmaxf(a0.z * 0.25f + b.z, 0.f);
  o.w = fmaxf(a0.w * 0.25f + b.w, 0.f);
  float accf = 0.f;
#pragma unroll
  for (int q = 0; q < 16; ++q) {
    float vx = __shfl(o.x, q), vy = __shfl(o.y, q);
    float vz = __shfl(o.z, q), vw = __shfl(o.w, q);
    accf = fmaf(vx, Wl[(4 * q + 0) * 64 + lane], accf);
    accf = fmaf(vy, Wl[(4 * q + 1) * 64 + lane], accf);
    accf = fmaf(vz, Wl[(4 * q + 2) * 64 + lane], accf);
    accf = fmaf(vw, Wl[(4 * q + 3) * 64 + lane], accf);
  }
  float v = accf + fcb[lane];
  if (lane < 32) {
    meanO[(long)n * 32 + lane] = v;
  } else {
    stdO[(long)n * 32 + (lane - 32)] =
        fmaxf(v, 0.f) + log1pf(__expf(-fabsf(v))) + 1e-6f;
  }
}

// Fused GAT layer, H=1 C=64, fp32 hs (bipartite): wave per node, lane=channel.
// 8 gathers in flight, 4 streams (per-stream order unchanged).
__device__ __forceinline__ void os1_upd(float& m, float& d, float& c, float l, float hv) {
  if (l > m) { float sc = __expf(m - l); d *= sc; c *= sc; m = l; }
  float ex = __expf(l - m);
  d += ex; c = fmaf(ex, hv, c);
}
__device__ __forceinline__ void os1_mrg(float& m0, float& d0, float& c0,
                                        float m1, float d1, float c1) {
  if (m1 == -INFINITY) return;
  if (m0 == -INFINITY) { m0 = m1; d0 = d1; c0 = c1; return; }
  float M = fmaxf(m0, m1);
  float sA = __expf(m0 - M), sB = __expf(m1 - M);
  d0 = d0 * sA + d1 * sB; c0 = c0 * sA + c1 * sB; m0 = M;
}

__global__ __launch_bounds__(256) void gat1_fused(
    int Nd, const int* __restrict__ dptr, const int2* __restrict__ csr_se,
    const float* __restrict__ al_s,
    const float* __restrict__ al_d, const float* __restrict__ dote,
    const float* __restrict__ hs, const float* __restrict__ bias,
    float* __restrict__ out) {
  int wave = threadIdx.x >> 6, lane = threadIdx.x & 63;
  int n = blockIdx.x * 4 + wave;
  if (n >= Nd) return;
  float ald = al_d[n];
  float de = dote[0];
  int e0 = dptr[n], e1 = dptr[n + 1];
  float m0 = -INFINITY, d0 = 0.f, c0 = 0.f;
  float m1 = -INFINITY, d1 = 0.f, c1 = 0.f;
  float m2 = -INFINITY, d2 = 0.f, c2 = 0.f;
  float m3 = -INFINITY, d3 = 0.f, c3 = 0.f;
  for (int base = e0; base < e1; base += 64) {
    int m = min(64, e1 - base);
    int sm = 0; float lm = 0.f;
    if (lane < m) {
      int2 v = csr_se[base + lane];
      sm = v.x;
      float ea = __int_as_float(v.y);
      lm = lrelu(al_s[sm] + ald + ea * de);
    }
    int j = 0;
    for (; j + 8 <= m; j += 8) {
      int s0 = __shfl(sm, j),     s1 = __shfl(sm, j + 1);
      int s2 = __shfl(sm, j + 2), s3 = __shfl(sm, j + 3);
      int s4 = __shfl(sm, j + 4), s5 = __shfl(sm, j + 5);
      int s6 = __shfl(sm, j + 6), s7 = __shfl(sm, j + 7);
      float l0 = __shfl(lm, j),     l1 = __shfl(lm, j + 1);
      float l2 = __shfl(lm, j + 2), l3 = __shfl(lm, j + 3);
      float l4 = __shfl(lm, j + 4), l5 = __shfl(lm, j + 5);
      float l6 = __shfl(lm, j + 6), l7 = __shfl(lm, j + 7);
      float h0 = hs[(long)s0 * 64 + lane];
      float h1 = hs[(long)s1 * 64 + lane];
      float h2 = hs[(long)s2 * 64 + lane];
      float h3 = hs[(long)s3 * 64 + lane];
      float h4 = hs[(long)s4 * 64 + lane];
      float h5 = hs[(long)s5 * 64 + lane];
      float h6 = hs[(long)s6 * 64 + lane];
      float h7 = hs[(long)s7 * 64 + lane];
      os1_upd(m0, d0, c0, l0, h0); os1_upd(m1, d1, c1, l1, h1);
      os1_upd(m2, d2, c2, l2, h2); os1_upd(m3, d3, c3, l3, h3);
      os1_upd(m0, d0, c0, l4, h4); os1_upd(m1, d1, c1, l5, h5);
      os1_upd(m2, d2, c2, l6, h6); os1_upd(m3, d3, c3, l7, h7);
    }
    for (; j + 4 <= m; j += 4) {
      int s0 = __shfl(sm, j), s1 = __shfl(sm, j + 1);
      int s2 = __shfl(sm, j + 2), s3 = __shfl(sm, j + 3);
      float l0 = __shfl(lm, j), l1 = __shfl(lm, j + 1);
      float l2 = __shfl(lm, j + 2), l3 = __shfl(lm, j + 3);
      float h0 = hs[(long)s0 * 64 + lane];
      float h1 = hs[(long)s1 * 64 + lane];
      float h2 = hs[(long)s2 * 64 + lane];
      float h3 = hs[(long)s3 * 64 + lane];
      os1_upd(m0, d0, c0, l0, h0); os1_upd(m1, d1, c1, l1, h1);
      os1_upd(m2, d2, c2, l2, h2); os1_upd(m3, d3, c3, l3, h3);
    }
    for (; j < m; ++j) {
      int s0 = __shfl(sm, j);
      float l0 = __shfl(lm, j);
      float h0 = hs[(long)s0 * 64 + lane];
      os1_upd(m0, d0, c0, l0, h0);
    }
  }
  os1_mrg(m0, d0, c0, m1, d1, c1);
  os1_mrg(m2, d2, c2, m3, d3, c3);
  os1_mrg(m0, d0, c0, m2, d2, c2);
  float o = c0 / (d0 + 1e-16f);
  out[(long)n * 64 + lane] = fmaxf(o + bias[lane], 0.f);
}

// ---------------------------------------------------------------------------
extern "C" void kernel_launch(void* const* d_in, const int* in_sizes, int n_in,
                              void* d_out, int out_size, void* d_ws, size_t ws_size,
                              hipStream_t stream) {
  const float* sp_mean = (const float*)d_in[0];
  const float* sp_std  = (const float*)d_in[1];
  const void*  nanmask = d_in[2];
  const float* sp_gen  = (const float*)d_in[3];
  const float* sp_phy  = (const float*)d_in[4];
  const float* spat_x  = (const float*)d_in[5];
  const float* spat_g  = (const float*)d_in[6];
  const int*   ss_ei   = (const int*)d_in[7];
  const float* ss_ea   = (const float*)d_in[8];
  const int*   bip_ei  = (const int*)d_in[9];
  const float* bip_ea  = (const float*)d_in[10];
  const int*   sp_ei   = (const int*)d_in[11];
  const float* sp_ea   = (const float*)d_in[12];
  const float* sg0_W = (const float*)d_in[13]; const float* sg0_as = (const float*)d_in[14];
  const float* sg0_ad = (const float*)d_in[15]; const float* sg0_ae = (const float*)d_in[16];
  const float* sg0_We = (const float*)d_in[17]; const float* sg0_b = (const float*)d_in[18];
  const float* sg1_W = (const float*)d_in[19]; const float* sg1_as = (const float*)d_in[20];
  const float* sg1_ad = (const float*)d_in[21]; const float* sg1_ae = (const float*)d_in[22];
  const float* sg1_We = (const float*)d_in[23]; const float* sg1_b = (const float*)d_in[24];
  const float* pg0_W = (const float*)d_in[25]; const float* pg0_as = (const float*)d_in[26];
  const float* pg0_ad = (const float*)d_in[27]; const float* pg0_ae = (const float*)d_in[28];
  const float* pg0_We = (const float*)d_in[29]; const float* pg0_b = (const float*)d_in[30];
  const float* pg1_W = (const float*)d_in[31]; const float* pg1_as = (const float*)d_in[32];
  const float* pg1_ad = (const float*)d_in[33]; const float* pg1_ae = (const float*)d_in[34];
  const float* pg1_We = (const float*)d_in[35]; const float* pg1_b = (const float*)d_in[36];
  const float* bp_Ws = (const float*)d_in[37]; const float* bp_Wd = (const float*)d_in[38];
  const float* bp_as = (const float*)d_in[39]; const float* bp_ad = (const float*)d_in[40];
  const float* bp_ae = (const float*)d_in[41]; const float* bp_We = (const float*)d_in[42];
  const float* bp_b  = (const float*)d_in[43];
  const float* sl_W  = (const float*)d_in[44]; const float* sl_b  = (const float*)d_in[45];
  const float* fc_W  = (const float*)d_in[46]; const float* fc_b  = (const float*)d_in[47];

  // ---- workspace layout ----
  char* wsb = (char*)d_ws;
  size_t off = 0;
  auto A = [&](size_t nbytes) -> void* {
    void* p = wsb + off;
    off += (nbytes + 255) & ~(size_t)255;
    return p;
  };
  // zero-initialized region: partition counters
  int* ss_cp = (int*)A((size_t)8 * NSPAT * 4);
  int* bp_cp = (int*)A((size_t)8 * NSP * 4);
  int* pp_cp = (int*)A((size_t)8 * NSP * 4);
  size_t zbytes = off;
  int*   ss_cnt = (int*)A((NSPAT + 1) * 4);
  int*   bp_cnt = (int*)A((NSP + 1) * 4);
  int*   pp_cnt = (int*)A((NSP + 1) * 4);
  float* dotes = (float*)A(5 * 4 * sizeof(float));
  float* alS   = (float*)A((size_t)NSP * 4 * 4);
  float* alD   = (float*)A((size_t)NSP * 4 * 4);
  float* alSb  = (float*)A((size_t)NSPAT * 4);
  float* alDb  = (float*)A((size_t)NSP * 4);
  float* spc96 = (float*)A((size_t)NSP * 96 * 4);
  float* sp_in = (float*)A((size_t)NSP * 64 * 4);
  float* h0    = (float*)A((size_t)NSPAT * 16 * 4);
  float* h_a   = (float*)A((size_t)NSPAT * 64 * 4);
  float* HS    = (float*)A((size_t)NSP * 256 * 4);   // bf16 hs rows
  float* sts   = (float*)A((size_t)NSP * 64 * 4);
  float* x1    = (float*)A((size_t)NSP * 64 * 4);
  int*   ss_ptr = (int*)A((NSPAT + 1) * 4);
  int2*  ss_se  = (int2*)A((size_t)ESS * 8);
  int*   ss_rnk = (int*)A((size_t)ESS * 4);
  int*   bp_ptr = (int*)A((NSP + 1) * 4);
  int2*  bp_se  = (int2*)A((size_t)EBIP * 8);
  int*   bp_rnk = (int*)A((size_t)EBIP * 4);
  int*   pp_ptr = (int*)A((NSP + 1) * 4);
  int2*  pp_se  = (int2*)A((size_t)ESP * 8);
  int*   pp_rnk = (int*)A((size_t)ESP * 4);
  (void)ws_size; (void)in_sizes; (void)n_in; (void)out_size;

  const int TB = 256;
  hipMemsetAsync(wsb, 0, zbytes, stream);

  // ---- L1: count + dote + spc96/h0 prep ----
  {
    DoteArgs da{};
    da.We[0] = sg0_We; da.ae[0] = sg0_ae;
    da.We[1] = sg1_We; da.ae[1] = sg1_ae;
    da.We[2] = bp_We;  da.ae[2] = bp_ae;
    da.We[3] = pg0_We; da.ae[3] = pg0_ae;
    da.We[4] = pg1_We; da.ae[4] = pg1_ae;
    da.dotes = dotes;
    PrepArgs pa{ sp_mean, sp_std, nanmask, spat_x, spat_g, spc96, h0 };
    int nb = cdiv_host(ESS + EBIP + ESP, TB) + 5 +
             cdiv_host((long)NSP * 96 + (long)NSPAT * 16, TB);
    count3x_kernel<<<nb, TB, 0, stream>>>(
        ss_ei + ESS, ss_cp, ss_rnk, NSPAT, ESS,
        bip_ei + EBIP, bp_cp, bp_rnk, NSP, EBIP,
        sp_ei + ESP, pp_cp, pp_rnk, NSP, ESP,
        da, pa);
  }
  // ---- L2: merge;  L3: scan ----
  merge3_kernel<<<cdiv_host(NSPAT + NSP + NSP, TB), TB, 0, stream>>>(
      ss_cp, ss_cnt, NSPAT, bp_cp, bp_cnt, NSP, pp_cp, pp_cnt, NSP);
  scan3_kernel<<<3, 1024, 0, stream>>>(ss_cnt, NSPAT, ss_ptr, bp_cnt, NSP, bp_ptr, pp_cnt, NSP, pp_ptr);

  // ---- L4: scatter + sg0 proj + sl proj + bp_Wd proj (one launch) ----
  {
    PJob jsl{}; jsl.xs.p[0] = spc96; jsl.xs.w[0] = 96; jsl.xs.p[1] = sp_gen; jsl.xs.w[1] = 64;
    jsl.xs.p[2] = sp_phy; jsl.xs.w[2] = 128; jsl.xs.n = 3;
    jsl.M = NSP; jsl.K = 288; jsl.W = sl_W; jsl.bias = sl_b; jsl.mode = 1; jsl.Y = sp_in;
    PJob jbp{}; jbp.xs.p[0] = sp_gen; jbp.xs.w[0] = 64; jbp.xs.p[1] = sp_phy; jbp.xs.w[1] = 128;
    jbp.xs.n = 2;
    jbp.M = NSP; jbp.K = 192; jbp.W = bp_Wd; jbp.mode = 0; jbp.a_d = bp_ad; jbp.al_d = alDb;
    XSrc xs0{}; xs0.p[0] = h0; xs0.w[0] = 16; xs0.n = 1;
    int nb_sc = cdiv_host(ESS + EBIP + ESP, TB);      // 3125
    int nb0 = cdiv_host(NSPAT, 32);                   // 313
    int nbsl = cdiv_host(NSP, 32);                    // 625
    int nbbp = cdiv_host(NSP, 32);                    // 625
    scatterproj_kernel<<<nb_sc + nb0 + nbsl + nbbp, TB, 0, stream>>>(
        ss_ei, ss_ei + ESS, ss_ea, ESS, ss_ptr, ss_cp, ss_rnk, NSPAT, ss_se,
        bip_ei, bip_ei + EBIP, bip_ea, EBIP, bp_ptr, bp_cp, bp_rnk, NSP, bp_se,
        sp_ei, sp_ei + ESP, sp_ea, ESP, pp_ptr, pp_cp, pp_rnk, NSP, pp_se,
        jsl, jbp,
        xs0, NSPAT, 16, sg0_W, sg0_as, sg0_ad, alS, alD, (unsigned short*)HS,
        nb0, nbsl);
  }

  // ---- spatial GNN ----
  gat4_fused<true><<<cdiv_host(NSPAT, 4), TB, 0, stream>>>(
      NSPAT, ss_ptr, ss_se, alS, alD, dotes + 0,
      (const unsigned short*)HS, sg0_b, h_a);
  {
    XSrc xs{}; xs.p[0] = h_a; xs.w[0] = 64; xs.n = 1;
    proj_kernel<<<cdiv_host(NSPAT, 32), TB, 0, stream>>>(xs, NSPAT, 64, sg1_W,
        sg1_as, sg1_ad, alS, alD, (unsigned short*)HS);
  }
  // sg1 GAT + fused bp_Ws source projection -> h_a (fp32 hs rows) + alSb
  gat4_bp<<<cdiv_host(NSPAT, 4), TB, 0, stream>>>(
      NSPAT, ss_ptr, ss_se, alS, alD, dotes + 4,
      (const unsigned short*)HS, sg1_b, bp_Ws, bp_as, h_a, alSb);

  // ---- bipartite GAT (spatial -> species), H=1, concat ----
  gat1_fused<<<cdiv_host(NSP, 4), TB, 0, stream>>>(
      NSP, bp_ptr, bp_se, alSb, alDb, dotes + 8, h_a, bp_b, sts);

  // ---- species GNN ----
  {
    XSrc xs{}; xs.p[0] = sts; xs.w[0] = 64; xs.p[1] = sp_in; xs.w[1] = 64; xs.n = 2;
    proj_kernel<<<cdiv_host(NSP, 32), TB, 0, stream>>>(xs, NSP, 128, pg0_W,
        pg0_as, pg0_ad, alS, alD, (unsigned short*)HS);
  }
  gat4_fused<true><<<cdiv_host(NSP, 4), TB, 0, stream>>>(
      NSP, pp_ptr, pp_se, alS, alD, dotes + 12,
      (const unsigned short*)HS, pg0_b, x1);
  {
    XSrc xs{}; xs.p[0] = x1; xs.w[0] = 64; xs.n = 1;
    proj_kernel<<<cdiv_host(NSP, 32), TB, 0, stream>>>(xs, NSP, 64, pg1_W,
        pg1_as, pg1_ad, alS, alD, (unsigned short*)HS);
  }
  // last GAT layer with fc + split/softplus fused — writes d_out directly
  gat4_fc<<<cdiv_host(NSP, 4), TB, 0, stream>>>(
      NSP, pp_ptr, pp_se, alS, alD, dotes + 16,
      (const unsigned short*)HS, pg1_b, fc_W, fc_b,
      (float*)d_out, (float*)d_out + (long)NSP * 32);
}